// Round 1
// baseline (856.382 us; speedup 1.0000x reference)
//
#include <hip/hip_runtime.h>

#define NNODES 50000
#define NEG 0.2f

// ---------------------------------------------------------------------------
// Precompute folded attention vectors: v[k] = sum_j W[k][j] * att[j]
// (a_src = h_src@att_src = x @ (W_src@att_src); same for dst)
// 4 vectors of 64: [v1_src, v1_dst, v2_src, v2_dst]
// ---------------------------------------------------------------------------
__global__ void prep_vecs(const float* __restrict__ W1s, const float* __restrict__ a1s,
                          const float* __restrict__ W1d, const float* __restrict__ a1d,
                          const float* __restrict__ W2s, const float* __restrict__ a2s,
                          const float* __restrict__ W2d, const float* __restrict__ a2d,
                          float* __restrict__ vecs) {
    int t = threadIdx.x;           // 256 threads
    int g = t >> 6, k = t & 63;
    const float* W = (g == 0) ? W1s : (g == 1) ? W1d : (g == 2) ? W2s : W2d;
    const float* a = (g == 0) ? a1s : (g == 1) ? a1d : (g == 2) ? a2s : a2d;
    float s = 0.f;
    #pragma unroll 8
    for (int j = 0; j < 64; ++j) s += W[k * 64 + j] * a[j];
    vecs[t] = s;
}

// ---------------------------------------------------------------------------
// Per-node kernel: for a 32-row tile,
//   hsrc = x @ Wsrc                      [rows,64]
//   agg  = x @ Wl + (b_conv + b_lin)     [rows,64]   (atomics add onto this)
//   asrc = x . vsrc, adst = x . vdst     [rows]
// Thread map: r = tid/8 (32 rows), cg = tid%8 -> 8 consecutive cols each.
// ---------------------------------------------------------------------------
__global__ __launch_bounds__(256) void node_gemm(
    const float* __restrict__ x, const float* __restrict__ Wsrc,
    const float* __restrict__ Wl, const float* __restrict__ vsrc,
    const float* __restrict__ vdst, const float* __restrict__ bconv,
    const float* __restrict__ blin,
    float* __restrict__ hsrc, float* __restrict__ agg,
    float* __restrict__ asrc, float* __restrict__ adst, int n) {
    __shared__ float Ws[64 * 64];
    __shared__ float Wls[64 * 64];
    __shared__ float xs[32 * 65];     // +1 pad: xs reads stride 64 would all hit one bank
    __shared__ float bias_s[64], vs_s[64], vd_s[64];

    int tid = threadIdx.x;
    #pragma unroll
    for (int i = 0; i < 16; ++i) {
        int idx = tid + i * 256;
        Ws[idx]  = Wsrc[idx];
        Wls[idx] = Wl[idx];
    }
    if (tid < 64) {
        bias_s[tid] = bconv[tid] + blin[tid];
        vs_s[tid]   = vsrc[tid];
        vd_s[tid]   = vdst[tid];
    }
    int row0 = blockIdx.x * 32;
    int rows = min(32, n - row0);
    #pragma unroll
    for (int i = 0; i < 8; ++i) {
        int idx = tid + i * 256;
        int r = idx >> 6, cc = idx & 63;
        if (r < rows) xs[r * 65 + cc] = x[(row0 + r) * 64 + cc];
    }
    __syncthreads();

    int r = tid >> 3, cg = tid & 7, c0 = cg * 8;
    if (r >= rows) return;

    float4 h0 = {0, 0, 0, 0}, h1 = {0, 0, 0, 0};
    float4 l0 = {0, 0, 0, 0}, l1 = {0, 0, 0, 0};
    float as = 0.f, ad = 0.f;
    #pragma unroll 8
    for (int k = 0; k < 64; ++k) {
        float xv = xs[r * 65 + k];
        float4 wa = *(const float4*)&Ws[(k << 6) + c0];
        float4 wb = *(const float4*)&Ws[(k << 6) + c0 + 4];
        float4 la = *(const float4*)&Wls[(k << 6) + c0];
        float4 lb = *(const float4*)&Wls[(k << 6) + c0 + 4];
        h0.x += xv * wa.x; h0.y += xv * wa.y; h0.z += xv * wa.z; h0.w += xv * wa.w;
        h1.x += xv * wb.x; h1.y += xv * wb.y; h1.z += xv * wb.z; h1.w += xv * wb.w;
        l0.x += xv * la.x; l0.y += xv * la.y; l0.z += xv * la.z; l0.w += xv * la.w;
        l1.x += xv * lb.x; l1.y += xv * lb.y; l1.z += xv * lb.z; l1.w += xv * lb.w;
        as += xv * vs_s[k];
        ad += xv * vd_s[k];
    }
    int rg = row0 + r;
    *(float4*)&hsrc[rg * 64 + c0]     = h0;
    *(float4*)&hsrc[rg * 64 + c0 + 4] = h1;
    float4 bA = *(const float4*)&bias_s[c0];
    float4 bB = *(const float4*)&bias_s[c0 + 4];
    l0.x += bA.x; l0.y += bA.y; l0.z += bA.z; l0.w += bA.w;
    l1.x += bB.x; l1.y += bB.y; l1.z += bB.z; l1.w += bB.w;
    *(float4*)&agg[rg * 64 + c0]     = l0;
    *(float4*)&agg[rg * 64 + c0 + 4] = l1;
    if (cg == 0) { asrc[rg] = as; adst[rg] = ad; }
}

// ---------------------------------------------------------------------------
// Edge pass 1: w = exp(leakyrelu(a_src[s] + a_dst[d])); segsum[d] += w
// (softmax max-subtraction dropped: mathematically identity, logits O(1))
// ---------------------------------------------------------------------------
__global__ void edge_softmax_num(const int* __restrict__ src, const int* __restrict__ dst,
                                 const float* __restrict__ asrc, const float* __restrict__ adst,
                                 float* __restrict__ segsum, float* __restrict__ wbuf, int E) {
    int i = blockIdx.x * blockDim.x + threadIdx.x;
    if (i >= E) return;
    int s = src[i], d = dst[i];
    float e = asrc[s] + adst[d];
    e = (e >= 0.f) ? e : NEG * e;
    float w = __expf(e);
    wbuf[i] = w;
    atomicAdd(&segsum[d], w);
}

// ---------------------------------------------------------------------------
// Edge pass 2: one wave (64 lanes) per edge; agg[d][c] += alpha * hsrc[s][c]
// ---------------------------------------------------------------------------
__global__ __launch_bounds__(256) void edge_scatter(const int* __restrict__ src,
                                                    const int* __restrict__ dst,
                                                    const float* __restrict__ wbuf,
                                                    const float* __restrict__ segsum,
                                                    const float* __restrict__ hsrc,
                                                    float* __restrict__ agg, int E) {
    int e = blockIdx.x * 4 + (threadIdx.x >> 6);
    int c = threadIdx.x & 63;
    if (e >= E) return;
    int s = src[e], d = dst[e];
    float alpha = wbuf[e] / segsum[d];
    atomicAdd(&agg[d * 64 + c], alpha * hsrc[s * 64 + c]);
}

__global__ void relu_k(const float* __restrict__ in, float* __restrict__ out, int n) {
    int i = blockIdx.x * blockDim.x + threadIdx.x;
    if (i < n) out[i] = fmaxf(in[i], 0.f);
}

// ---------------------------------------------------------------------------
extern "C" void kernel_launch(void* const* d_in, const int* in_sizes, int n_in,
                              void* d_out, int out_size, void* d_ws, size_t ws_size,
                              hipStream_t stream) {
    const float* x    = (const float*)d_in[0];
    const int*   ei   = (const int*)d_in[1];
    const float* W1s  = (const float*)d_in[2];
    const float* W1d  = (const float*)d_in[3];
    const float* a1s  = (const float*)d_in[4];
    const float* a1d  = (const float*)d_in[5];
    const float* b1   = (const float*)d_in[6];
    const float* Wl1  = (const float*)d_in[7];
    const float* bl1  = (const float*)d_in[8];
    const float* W2s  = (const float*)d_in[9];
    const float* W2d  = (const float*)d_in[10];
    const float* a2s  = (const float*)d_in[11];
    const float* a2d  = (const float*)d_in[12];
    const float* b2   = (const float*)d_in[13];
    const float* Wl2  = (const float*)d_in[14];
    const float* bl2  = (const float*)d_in[15];

    const int N = in_sizes[0] / 64;          // 50000
    const int E = in_sizes[1] / 2;           // 1200000
    const int* src = ei;
    const int* dst = ei + E;

    float* ws = (float*)d_ws;
    size_t o = 0;
    float* hsrc   = ws + o; o += (size_t)N * 64;
    float* agg    = ws + o; o += (size_t)N * 64;
    float* hmid   = ws + o; o += (size_t)N * 64;
    float* asrc   = ws + o; o += N;
    float* adst   = ws + o; o += N;
    float* segsum = ws + o; o += N;
    float* wbuf   = ws + o; o += E;
    float* vecs   = ws + o; o += 256;

    prep_vecs<<<1, 256, 0, stream>>>(W1s, a1s, W1d, a1d, W2s, a2s, W2d, a2d, vecs);

    // ---- conv1 ----
    node_gemm<<<(N + 31) / 32, 256, 0, stream>>>(x, W1s, Wl1, vecs, vecs + 64,
                                                 b1, bl1, hsrc, agg, asrc, adst, N);
    hipMemsetAsync(segsum, 0, (size_t)N * sizeof(float), stream);
    edge_softmax_num<<<(E + 255) / 256, 256, 0, stream>>>(src, dst, asrc, adst, segsum, wbuf, E);
    edge_scatter<<<(E + 3) / 4, 256, 0, stream>>>(src, dst, wbuf, segsum, hsrc, agg, E);
    relu_k<<<(N * 64 + 255) / 256, 256, 0, stream>>>(agg, hmid, N * 64);

    // ---- conv2 ----
    node_gemm<<<(N + 31) / 32, 256, 0, stream>>>(hmid, W2s, Wl2, vecs + 128, vecs + 192,
                                                 b2, bl2, hsrc, agg, asrc, adst, N);
    hipMemsetAsync(segsum, 0, (size_t)N * sizeof(float), stream);
    edge_softmax_num<<<(E + 255) / 256, 256, 0, stream>>>(src, dst, asrc, adst, segsum, wbuf, E);
    edge_scatter<<<(E + 3) / 4, 256, 0, stream>>>(src, dst, wbuf, segsum, hsrc, agg, E);
    relu_k<<<(N * 64 + 255) / 256, 256, 0, stream>>>(agg, (float*)d_out, N * 64);
}

// Round 2
// 489.343 us; speedup vs baseline: 1.7501x; 1.7501x over previous
//
#include <hip/hip_runtime.h>

#define NEG 0.2f

// ---------------------------------------------------------------------------
// Precompute folded attention vectors: v[k] = sum_j W[k][j] * att[j]
// (a_src = (x@W_src)@att_src = x @ (W_src@att_src); same for dst)
// 4 vectors of 64: [v1_src, v1_dst, v2_src, v2_dst]
// ---------------------------------------------------------------------------
__global__ void prep_vecs(const float* __restrict__ W1s, const float* __restrict__ a1s,
                          const float* __restrict__ W1d, const float* __restrict__ a1d,
                          const float* __restrict__ W2s, const float* __restrict__ a2s,
                          const float* __restrict__ W2d, const float* __restrict__ a2d,
                          float* __restrict__ vecs) {
    int t = threadIdx.x;           // 256 threads
    int g = t >> 6, k = t & 63;
    const float* W = (g == 0) ? W1s : (g == 1) ? W1d : (g == 2) ? W2s : W2d;
    const float* a = (g == 0) ? a1s : (g == 1) ? a1d : (g == 2) ? a2s : a2d;
    float s = 0.f;
    #pragma unroll 8
    for (int j = 0; j < 64; ++j) s += W[k * 64 + j] * a[j];
    vecs[t] = s;
}

// ---------------------------------------------------------------------------
// Per-node kernel (32-row tile):
//   hsrc = x @ Wsrc                      [rows,64]
//   base = x @ Wl + (b_conv + b_lin)     [rows,64]
//   asrc = x . vsrc, adst = x . vdst     [rows]
// ---------------------------------------------------------------------------
__global__ __launch_bounds__(256) void node_gemm(
    const float* __restrict__ x, const float* __restrict__ Wsrc,
    const float* __restrict__ Wl, const float* __restrict__ vsrc,
    const float* __restrict__ vdst, const float* __restrict__ bconv,
    const float* __restrict__ blin,
    float* __restrict__ hsrc, float* __restrict__ base_out,
    float* __restrict__ asrc, float* __restrict__ adst, int n) {
    __shared__ float Ws[64 * 64];
    __shared__ float Wls[64 * 64];
    __shared__ float xs[32 * 65];
    __shared__ float bias_s[64], vs_s[64], vd_s[64];

    int tid = threadIdx.x;
    #pragma unroll
    for (int i = 0; i < 16; ++i) {
        int idx = tid + i * 256;
        Ws[idx]  = Wsrc[idx];
        Wls[idx] = Wl[idx];
    }
    if (tid < 64) {
        bias_s[tid] = bconv[tid] + blin[tid];
        vs_s[tid]   = vsrc[tid];
        vd_s[tid]   = vdst[tid];
    }
    int row0 = blockIdx.x * 32;
    int rows = min(32, n - row0);
    #pragma unroll
    for (int i = 0; i < 8; ++i) {
        int idx = tid + i * 256;
        int r = idx >> 6, cc = idx & 63;
        if (r < rows) xs[r * 65 + cc] = x[(row0 + r) * 64 + cc];
    }
    __syncthreads();

    int r = tid >> 3, cg = tid & 7, c0 = cg * 8;
    if (r >= rows) return;

    float4 h0 = {0, 0, 0, 0}, h1 = {0, 0, 0, 0};
    float4 l0 = {0, 0, 0, 0}, l1 = {0, 0, 0, 0};
    float as = 0.f, ad = 0.f;
    #pragma unroll 8
    for (int k = 0; k < 64; ++k) {
        float xv = xs[r * 65 + k];
        float4 wa = *(const float4*)&Ws[(k << 6) + c0];
        float4 wb = *(const float4*)&Ws[(k << 6) + c0 + 4];
        float4 la = *(const float4*)&Wls[(k << 6) + c0];
        float4 lb = *(const float4*)&Wls[(k << 6) + c0 + 4];
        h0.x += xv * wa.x; h0.y += xv * wa.y; h0.z += xv * wa.z; h0.w += xv * wa.w;
        h1.x += xv * wb.x; h1.y += xv * wb.y; h1.z += xv * wb.z; h1.w += xv * wb.w;
        l0.x += xv * la.x; l0.y += xv * la.y; l0.z += xv * la.z; l0.w += xv * la.w;
        l1.x += xv * lb.x; l1.y += xv * lb.y; l1.z += xv * lb.z; l1.w += xv * lb.w;
        as += xv * vs_s[k];
        ad += xv * vd_s[k];
    }
    int rg = row0 + r;
    *(float4*)&hsrc[rg * 64 + c0]     = h0;
    *(float4*)&hsrc[rg * 64 + c0 + 4] = h1;
    float4 bA = *(const float4*)&bias_s[c0];
    float4 bB = *(const float4*)&bias_s[c0 + 4];
    l0.x += bA.x; l0.y += bA.y; l0.z += bA.z; l0.w += bA.w;
    l1.x += bB.x; l1.y += bB.y; l1.z += bB.z; l1.w += bB.w;
    *(float4*)&base_out[rg * 64 + c0]     = l0;
    *(float4*)&base_out[rg * 64 + c0 + 4] = l1;
    if (cg == 0) { asrc[rg] = as; adst[rg] = ad; }
}

// ---------------------------------------------------------------------------
// CSR build: histogram -> hierarchical exclusive scan -> placement
// ---------------------------------------------------------------------------
__global__ void hist_k(const int* __restrict__ dst, int* __restrict__ deg, int E) {
    int i = blockIdx.x * blockDim.x + threadIdx.x;
    if (i < E) atomicAdd(&deg[dst[i]], 1);
}

// each block sums 1024 elements of deg (thread t -> elems [t*4, t*4+4))
__global__ __launch_bounds__(256) void partial_k(const int* __restrict__ deg,
                                                 int* __restrict__ bsum, int N) {
    __shared__ int sm[256];
    int b = blockIdx.x, t = threadIdx.x;
    int base = b * 1024 + t * 4;
    int s = 0;
    #pragma unroll
    for (int i = 0; i < 4; ++i) { int idx = base + i; if (idx < N) s += deg[idx]; }
    sm[t] = s; __syncthreads();
    for (int off = 128; off > 0; off >>= 1) {
        if (t < off) sm[t] += sm[t + off];
        __syncthreads();
    }
    if (t == 0) bsum[b] = sm[0];
}

__global__ void scan_bsum_k(int* __restrict__ bsum, int nb,
                            int* __restrict__ rowptr, int N, int E) {
    if (threadIdx.x == 0 && blockIdx.x == 0) {
        int run = 0;
        for (int i = 0; i < nb; ++i) { int v = bsum[i]; bsum[i] = run; run += v; }
        rowptr[N] = E;
    }
}

__global__ __launch_bounds__(256) void scan_final_k(const int* __restrict__ deg,
                                                    const int* __restrict__ bsum,
                                                    int* __restrict__ rowptr,
                                                    int* __restrict__ cursor, int N) {
    __shared__ int sm[256];
    int b = blockIdx.x, t = threadIdx.x;
    int base = b * 1024 + t * 4;
    int d0 = (base + 0 < N) ? deg[base + 0] : 0;
    int d1 = (base + 1 < N) ? deg[base + 1] : 0;
    int d2 = (base + 2 < N) ? deg[base + 2] : 0;
    int d3 = (base + 3 < N) ? deg[base + 3] : 0;
    int tsum = d0 + d1 + d2 + d3;
    sm[t] = tsum; __syncthreads();
    // Hillis-Steele inclusive scan over 256 thread sums
    for (int off = 1; off < 256; off <<= 1) {
        int v = (t >= off) ? sm[t - off] : 0;
        __syncthreads();
        sm[t] += v;
        __syncthreads();
    }
    int p0 = sm[t] - tsum + bsum[b];
    int p1 = p0 + d0, p2 = p1 + d1, p3 = p2 + d2;
    if (base + 0 < N) { rowptr[base + 0] = p0; cursor[base + 0] = p0; }
    if (base + 1 < N) { rowptr[base + 1] = p1; cursor[base + 1] = p1; }
    if (base + 2 < N) { rowptr[base + 2] = p2; cursor[base + 2] = p2; }
    if (base + 3 < N) { rowptr[base + 3] = p3; cursor[base + 3] = p3; }
}

__global__ void place_k(const int* __restrict__ src, const int* __restrict__ dst,
                        int* __restrict__ cursor, int* __restrict__ ssrc, int E) {
    int i = blockIdx.x * blockDim.x + threadIdx.x;
    if (i >= E) return;
    int pos = atomicAdd(&cursor[dst[i]], 1);
    ssrc[pos] = src[i];
}

// ---------------------------------------------------------------------------
// Fused softmax + aggregation + residual + relu. One wave per dst node,
// lane = channel. out[d] = relu(base[d] + (Σ_j w_j * hsrc[s_j]) / Σ_j w_j)
// ---------------------------------------------------------------------------
__global__ __launch_bounds__(256) void gat_aggregate(
    const int* __restrict__ rowptr, const int* __restrict__ ssrc,
    const float* __restrict__ asrc, const float* __restrict__ adst,
    const float* __restrict__ hsrc, const float* __restrict__ base,
    float* __restrict__ out, int N) {
    int d = blockIdx.x * 4 + (threadIdx.x >> 6);
    int c = threadIdx.x & 63;
    if (d >= N) return;
    int j = rowptr[d], end = rowptr[d + 1];
    float ad = adst[d];
    float sumw = 0.f, acc = 0.f;
    for (; j + 2 <= end; j += 2) {
        int s0 = ssrc[j], s1 = ssrc[j + 1];
        float e0 = asrc[s0] + ad, e1 = asrc[s1] + ad;
        e0 = (e0 >= 0.f) ? e0 : NEG * e0;
        e1 = (e1 >= 0.f) ? e1 : NEG * e1;
        float w0 = __expf(e0), w1 = __expf(e1);
        float h0 = hsrc[s0 * 64 + c], h1 = hsrc[s1 * 64 + c];
        sumw += w0 + w1;
        acc += w0 * h0 + w1 * h1;
    }
    if (j < end) {
        int s = ssrc[j];
        float e = asrc[s] + ad;
        e = (e >= 0.f) ? e : NEG * e;
        float w = __expf(e);
        sumw += w;
        acc += w * hsrc[s * 64 + c];
    }
    float r = base[d * 64 + c];
    if (sumw > 0.f) r += acc / sumw;
    out[d * 64 + c] = fmaxf(r, 0.f);
}

// ---------------------------------------------------------------------------
extern "C" void kernel_launch(void* const* d_in, const int* in_sizes, int n_in,
                              void* d_out, int out_size, void* d_ws, size_t ws_size,
                              hipStream_t stream) {
    const float* x    = (const float*)d_in[0];
    const int*   ei   = (const int*)d_in[1];
    const float* W1s  = (const float*)d_in[2];
    const float* W1d  = (const float*)d_in[3];
    const float* a1s  = (const float*)d_in[4];
    const float* a1d  = (const float*)d_in[5];
    const float* b1   = (const float*)d_in[6];
    const float* Wl1  = (const float*)d_in[7];
    const float* bl1  = (const float*)d_in[8];
    const float* W2s  = (const float*)d_in[9];
    const float* W2d  = (const float*)d_in[10];
    const float* a2s  = (const float*)d_in[11];
    const float* a2d  = (const float*)d_in[12];
    const float* b2   = (const float*)d_in[13];
    const float* Wl2  = (const float*)d_in[14];
    const float* bl2  = (const float*)d_in[15];

    const int N = in_sizes[0] / 64;          // 50000
    const int E = in_sizes[1] / 2;           // 1200000
    const int* src = ei;
    const int* dst = ei + E;
    const int NB = (N + 1023) / 1024;        // scan blocks

    float* ws = (float*)d_ws;
    size_t o = 0;
    float* hsrc   = ws + o; o += (size_t)N * 64;
    float* base   = ws + o; o += (size_t)N * 64;
    float* asrc   = ws + o; o += N;
    float* adst   = ws + o; o += N;
    float* vecs   = ws + o; o += 256;
    int* rowptr = (int*)(ws + o); o += N + 1;
    int* cursor = (int*)(ws + o); o += N;
    int* bsum   = (int*)(ws + o); o += NB + 1;
    int* ssrc   = (int*)(ws + o); o += E;
    int* deg    = ssrc;   // deg dead before ssrc is written (place_k after scan_final_k)

    float* hmid = (float*)d_out;  // conv1 output scratch; conv2 overwrites d_out last

    prep_vecs<<<1, 256, 0, stream>>>(W1s, a1s, W1d, a1d, W2s, a2s, W2d, a2d, vecs);

    // ---- CSR build (once; shared by both convs) ----
    hipMemsetAsync(deg, 0, (size_t)N * sizeof(int), stream);
    hist_k<<<(E + 255) / 256, 256, 0, stream>>>(dst, deg, E);
    partial_k<<<NB, 256, 0, stream>>>(deg, bsum, N);
    scan_bsum_k<<<1, 64, 0, stream>>>(bsum, NB, rowptr, N, E);
    scan_final_k<<<NB, 256, 0, stream>>>(deg, bsum, rowptr, cursor, N);
    place_k<<<(E + 255) / 256, 256, 0, stream>>>(src, dst, cursor, ssrc, E);

    // ---- conv1 ----
    node_gemm<<<(N + 31) / 32, 256, 0, stream>>>(x, W1s, Wl1, vecs, vecs + 64,
                                                 b1, bl1, hsrc, base, asrc, adst, N);
    gat_aggregate<<<(N + 3) / 4, 256, 0, stream>>>(rowptr, ssrc, asrc, adst,
                                                   hsrc, base, hmid, N);

    // ---- conv2 ----
    node_gemm<<<(N + 31) / 32, 256, 0, stream>>>(hmid, W2s, Wl2, vecs + 128, vecs + 192,
                                                 b2, bl2, hsrc, base, asrc, adst, N);
    gat_aggregate<<<(N + 3) / 4, 256, 0, stream>>>(rowptr, ssrc, asrc, adst,
                                                   hsrc, base, (float*)d_out, N);
}

// Round 3
// 397.336 us; speedup vs baseline: 2.1553x; 1.2316x over previous
//
#include <hip/hip_runtime.h>

#define NEG 0.2f
#define BSHIFT 9
#define BNODES 512          // dst nodes per bucket
#define ECAP 14336          // max edges per bucket (mean ~12288, sd ~110 -> 18 sigma)

// ---------------------------------------------------------------------------
// Precompute folded attention vectors: v[k] = sum_j W[k][j] * att[j]
// ---------------------------------------------------------------------------
__global__ void prep_vecs(const float* __restrict__ W1s, const float* __restrict__ a1s,
                          const float* __restrict__ W1d, const float* __restrict__ a1d,
                          const float* __restrict__ W2s, const float* __restrict__ a2s,
                          const float* __restrict__ W2d, const float* __restrict__ a2d,
                          float* __restrict__ vecs) {
    int t = threadIdx.x;           // 256 threads
    int g = t >> 6, k = t & 63;
    const float* W = (g == 0) ? W1s : (g == 1) ? W1d : (g == 2) ? W2s : W2d;
    const float* a = (g == 0) ? a1s : (g == 1) ? a1d : (g == 2) ? a2s : a2d;
    float s = 0.f;
    #pragma unroll 8
    for (int j = 0; j < 64; ++j) s += W[k * 64 + j] * a[j];
    vecs[t] = s;
}

// ---------------------------------------------------------------------------
// Per-node kernel (32-row tile):
//   hsrc = x @ Wsrc ; base = x @ Wl + (b_conv+b_lin) ; asrc = x.vsrc ; adst = x.vdst
// ---------------------------------------------------------------------------
__global__ __launch_bounds__(256) void node_gemm(
    const float* __restrict__ x, const float* __restrict__ Wsrc,
    const float* __restrict__ Wl, const float* __restrict__ vsrc,
    const float* __restrict__ vdst, const float* __restrict__ bconv,
    const float* __restrict__ blin,
    float* __restrict__ hsrc, float* __restrict__ base_out,
    float* __restrict__ asrc, float* __restrict__ adst, int n) {
    __shared__ float Ws[64 * 64];
    __shared__ float Wls[64 * 64];
    __shared__ float xs[32 * 65];
    __shared__ float bias_s[64], vs_s[64], vd_s[64];

    int tid = threadIdx.x;
    #pragma unroll
    for (int i = 0; i < 16; ++i) {
        int idx = tid + i * 256;
        Ws[idx]  = Wsrc[idx];
        Wls[idx] = Wl[idx];
    }
    if (tid < 64) {
        bias_s[tid] = bconv[tid] + blin[tid];
        vs_s[tid]   = vsrc[tid];
        vd_s[tid]   = vdst[tid];
    }
    int row0 = blockIdx.x * 32;
    int rows = min(32, n - row0);
    #pragma unroll
    for (int i = 0; i < 8; ++i) {
        int idx = tid + i * 256;
        int r = idx >> 6, cc = idx & 63;
        if (r < rows) xs[r * 65 + cc] = x[(row0 + r) * 64 + cc];
    }
    __syncthreads();

    int r = tid >> 3, cg = tid & 7, c0 = cg * 8;
    if (r >= rows) return;

    float4 h0 = {0, 0, 0, 0}, h1 = {0, 0, 0, 0};
    float4 l0 = {0, 0, 0, 0}, l1 = {0, 0, 0, 0};
    float as = 0.f, ad = 0.f;
    #pragma unroll 8
    for (int k = 0; k < 64; ++k) {
        float xv = xs[r * 65 + k];
        float4 wa = *(const float4*)&Ws[(k << 6) + c0];
        float4 wb = *(const float4*)&Ws[(k << 6) + c0 + 4];
        float4 la = *(const float4*)&Wls[(k << 6) + c0];
        float4 lb = *(const float4*)&Wls[(k << 6) + c0 + 4];
        h0.x += xv * wa.x; h0.y += xv * wa.y; h0.z += xv * wa.z; h0.w += xv * wa.w;
        h1.x += xv * wb.x; h1.y += xv * wb.y; h1.z += xv * wb.z; h1.w += xv * wb.w;
        l0.x += xv * la.x; l0.y += xv * la.y; l0.z += xv * la.z; l0.w += xv * la.w;
        l1.x += xv * lb.x; l1.y += xv * lb.y; l1.z += xv * lb.z; l1.w += xv * lb.w;
        as += xv * vs_s[k];
        ad += xv * vd_s[k];
    }
    int rg = row0 + r;
    *(float4*)&hsrc[rg * 64 + c0]     = h0;
    *(float4*)&hsrc[rg * 64 + c0 + 4] = h1;
    float4 bA = *(const float4*)&bias_s[c0];
    float4 bB = *(const float4*)&bias_s[c0 + 4];
    l0.x += bA.x; l0.y += bA.y; l0.z += bA.z; l0.w += bA.w;
    l1.x += bB.x; l1.y += bB.y; l1.z += bB.z; l1.w += bB.w;
    *(float4*)&base_out[rg * 64 + c0]     = l0;
    *(float4*)&base_out[rg * 64 + c0 + 4] = l1;
    if (cg == 0) { asrc[rg] = as; adst[rg] = ad; }
}

// ---------------------------------------------------------------------------
// Pass 1: coarse bucket histogram (bucket = dst >> 9). LDS-aggregated.
// ---------------------------------------------------------------------------
__global__ __launch_bounds__(256) void bucket_hist(const int* __restrict__ dst,
                                                   int* __restrict__ bcnt, int E, int K) {
    __shared__ int h[128];
    int t = threadIdx.x;
    if (t < 128) h[t] = 0;
    __syncthreads();
    int base = blockIdx.x * 2048;
    #pragma unroll
    for (int i = 0; i < 8; ++i) {
        int idx = base + i * 256 + t;
        if (idx < E) atomicAdd(&h[dst[idx] >> BSHIFT], 1);
    }
    __syncthreads();
    if (t < K && h[t]) atomicAdd(&bcnt[t], h[t]);
}

// tiny scan over K buckets; also seeds global cursors and rowptr[N]
__global__ void bucket_scan(const int* __restrict__ bcnt, int* __restrict__ bbase,
                            int* __restrict__ gcur, int* __restrict__ rowptr,
                            int K, int N, int E) {
    if (threadIdx.x == 0 && blockIdx.x == 0) {
        int run = 0;
        for (int i = 0; i < K; ++i) { bbase[i] = run; gcur[i] = run; run += bcnt[i]; }
        bbase[K] = run;
        rowptr[N] = E;
    }
}

// ---------------------------------------------------------------------------
// Pass 2: bin edges into bucket regions, packed (src<<9 | dst&511).
// Per-block LDS hist -> one chunk-reservation atomic per (block,bucket) ->
// contiguous chunk writes (kills the 16x write amplification of random scatter).
// ---------------------------------------------------------------------------
__global__ __launch_bounds__(256) void bin_scatter(const int* __restrict__ src,
                                                   const int* __restrict__ dst,
                                                   int* __restrict__ gcur,
                                                   unsigned* __restrict__ binned,
                                                   int E, int K) {
    __shared__ int h[128], cbase[128], cur[128];
    int t = threadIdx.x;
    if (t < 128) h[t] = 0;
    __syncthreads();
    int base = blockIdx.x * 2048;
    #pragma unroll
    for (int i = 0; i < 8; ++i) {
        int idx = base + i * 256 + t;
        if (idx < E) atomicAdd(&h[dst[idx] >> BSHIFT], 1);
    }
    __syncthreads();
    if (t < K) {
        cbase[t] = h[t] ? atomicAdd(&gcur[t], h[t]) : 0;
        cur[t] = 0;
    }
    __syncthreads();
    #pragma unroll
    for (int i = 0; i < 8; ++i) {
        int idx = base + i * 256 + t;
        if (idx < E) {
            int d = dst[idx], s = src[idx];
            int b = d >> BSHIFT;
            int pos = cbase[b] + atomicAdd(&cur[b], 1);
            binned[pos] = ((unsigned)s << BSHIFT) | (unsigned)(d & (BNODES - 1));
        }
    }
}

// ---------------------------------------------------------------------------
// Pass 3: one block per bucket. Stage bucket edges in LDS, local hist+scan,
// write rowptr (coalesced) and scatter src back IN-PLACE over the binned
// region (48 KB target -> L2 absorbs, no write amplification).
// ---------------------------------------------------------------------------
__global__ __launch_bounds__(1024) void local_csr(const unsigned* __restrict__ binned_in,
                                                  int* __restrict__ ssrc_out,   // same buffer
                                                  const int* __restrict__ bbase,
                                                  int* __restrict__ rowptr, int N) {
    __shared__ int lh[BNODES];     // hist, later cursor
    __shared__ int lex[BNODES];    // exclusive prefix
    __shared__ unsigned ebuf[ECAP];
    int b = blockIdx.x, t = threadIdx.x;
    int base = bbase[b];
    int cnt = min(bbase[b + 1] - base, ECAP);
    if (t < BNODES) lh[t] = 0;
    __syncthreads();
    for (int i = t; i < cnt; i += 1024) {
        unsigned e = binned_in[base + i];
        ebuf[i] = e;
        atomicAdd(&lh[e & (BNODES - 1)], 1);
    }
    __syncthreads();
    // inclusive scan of lh into lex (Hillis-Steele over 512 entries)
    if (t < BNODES) lex[t] = lh[t];
    __syncthreads();
    for (int off = 1; off < BNODES; off <<= 1) {
        int add = 0;
        if (t < BNODES && t >= off) add = lex[t - off];
        __syncthreads();
        if (t < BNODES) lex[t] += add;
        __syncthreads();
    }
    int exc = 0;
    if (t < BNODES) exc = lex[t] - lh[t];
    __syncthreads();
    if (t < BNODES) { lex[t] = exc; lh[t] = exc; }   // lh becomes cursor
    __syncthreads();
    int node = b * BNODES + t;
    if (t < BNODES && node < N) rowptr[node] = base + lex[t];
    for (int i = t; i < cnt; i += 1024) {
        unsigned e = ebuf[i];
        int pos = atomicAdd(&lh[e & (BNODES - 1)], 1);
        ssrc_out[base + pos] = (int)(e >> BSHIFT);
    }
}

// ---------------------------------------------------------------------------
// Fused softmax + aggregation + residual + relu. One wave per dst node.
// ---------------------------------------------------------------------------
__global__ __launch_bounds__(256) void gat_aggregate(
    const int* __restrict__ rowptr, const int* __restrict__ ssrc,
    const float* __restrict__ asrc, const float* __restrict__ adst,
    const float* __restrict__ hsrc, const float* __restrict__ base,
    float* __restrict__ out, int N) {
    int d = blockIdx.x * 4 + (threadIdx.x >> 6);
    int c = threadIdx.x & 63;
    if (d >= N) return;
    int j = rowptr[d], end = rowptr[d + 1];
    float ad = adst[d];
    float sumw = 0.f, acc = 0.f;
    for (; j + 2 <= end; j += 2) {
        int s0 = ssrc[j], s1 = ssrc[j + 1];
        float e0 = asrc[s0] + ad, e1 = asrc[s1] + ad;
        e0 = (e0 >= 0.f) ? e0 : NEG * e0;
        e1 = (e1 >= 0.f) ? e1 : NEG * e1;
        float w0 = __expf(e0), w1 = __expf(e1);
        float h0 = hsrc[s0 * 64 + c], h1 = hsrc[s1 * 64 + c];
        sumw += w0 + w1;
        acc += w0 * h0 + w1 * h1;
    }
    if (j < end) {
        int s = ssrc[j];
        float e = asrc[s] + ad;
        e = (e >= 0.f) ? e : NEG * e;
        float w = __expf(e);
        sumw += w;
        acc += w * hsrc[s * 64 + c];
    }
    float r = base[d * 64 + c];
    if (sumw > 0.f) r += acc / sumw;
    out[d * 64 + c] = fmaxf(r, 0.f);
}

// ---------------------------------------------------------------------------
extern "C" void kernel_launch(void* const* d_in, const int* in_sizes, int n_in,
                              void* d_out, int out_size, void* d_ws, size_t ws_size,
                              hipStream_t stream) {
    const float* x    = (const float*)d_in[0];
    const int*   ei   = (const int*)d_in[1];
    const float* W1s  = (const float*)d_in[2];
    const float* W1d  = (const float*)d_in[3];
    const float* a1s  = (const float*)d_in[4];
    const float* a1d  = (const float*)d_in[5];
    const float* b1   = (const float*)d_in[6];
    const float* Wl1  = (const float*)d_in[7];
    const float* bl1  = (const float*)d_in[8];
    const float* W2s  = (const float*)d_in[9];
    const float* W2d  = (const float*)d_in[10];
    const float* a2s  = (const float*)d_in[11];
    const float* a2d  = (const float*)d_in[12];
    const float* b2   = (const float*)d_in[13];
    const float* Wl2  = (const float*)d_in[14];
    const float* bl2  = (const float*)d_in[15];

    const int N = in_sizes[0] / 64;          // 50000
    const int E = in_sizes[1] / 2;           // 1200000
    const int* src = ei;
    const int* dst = ei + E;
    const int K = (N + BNODES - 1) >> BSHIFT;  // 98 buckets (<=128)

    float* ws = (float*)d_ws;
    size_t o = 0;
    float* hsrc   = ws + o; o += (size_t)N * 64;
    float* base   = ws + o; o += (size_t)N * 64;
    float* asrc   = ws + o; o += N;
    float* adst   = ws + o; o += N;
    float* vecs   = ws + o; o += 256;
    int* rowptr = (int*)(ws + o); o += N + 1;
    int* bcnt   = (int*)(ws + o); o += 128;
    int* bbase  = (int*)(ws + o); o += 129;
    int* gcur   = (int*)(ws + o); o += 128;
    unsigned* binned = (unsigned*)(ws + o); o += E;   // also final ssrc (in-place)
    int* ssrc = (int*)binned;

    float* hmid = (float*)d_out;  // conv1 output scratch; conv2 overwrites d_out last

    prep_vecs<<<1, 256, 0, stream>>>(W1s, a1s, W1d, a1d, W2s, a2s, W2d, a2d, vecs);

    // ---- CSR build via two-level LDS binning (once; shared by both convs) ----
    hipMemsetAsync(bcnt, 0, 128 * sizeof(int), stream);
    const int EB = (E + 2047) / 2048;
    bucket_hist<<<EB, 256, 0, stream>>>(dst, bcnt, E, K);
    bucket_scan<<<1, 64, 0, stream>>>(bcnt, bbase, gcur, rowptr, K, N, E);
    bin_scatter<<<EB, 256, 0, stream>>>(src, dst, gcur, binned, E, K);
    local_csr<<<K, 1024, 0, stream>>>(binned, ssrc, bbase, rowptr, N);

    // ---- conv1 ----
    node_gemm<<<(N + 31) / 32, 256, 0, stream>>>(x, W1s, Wl1, vecs, vecs + 64,
                                                 b1, bl1, hsrc, base, asrc, adst, N);
    gat_aggregate<<<(N + 3) / 4, 256, 0, stream>>>(rowptr, ssrc, asrc, adst,
                                                   hsrc, base, hmid, N);

    // ---- conv2 ----
    node_gemm<<<(N + 31) / 32, 256, 0, stream>>>(hmid, W2s, Wl2, vecs + 128, vecs + 192,
                                                 b2, bl2, hsrc, base, asrc, adst, N);
    gat_aggregate<<<(N + 3) / 4, 256, 0, stream>>>(rowptr, ssrc, asrc, adst,
                                                   hsrc, base, (float*)d_out, N);
}

// Round 4
// 334.740 us; speedup vs baseline: 2.5583x; 1.1870x over previous
//
#include <hip/hip_runtime.h>
#include <hip/hip_fp16.h>

#define NEG 0.2f
#define BSHIFT 9
#define BNODES 512          // dst nodes per bucket
#define ECAP 14336          // max edges per bucket (mean ~12288, sd ~110 -> 18 sigma)

// ---------------------------------------------------------------------------
// Precompute folded attention vectors: v[k] = sum_j W[k][j] * att[j]
// ---------------------------------------------------------------------------
__global__ void prep_vecs(const float* __restrict__ W1s, const float* __restrict__ a1s,
                          const float* __restrict__ W1d, const float* __restrict__ a1d,
                          const float* __restrict__ W2s, const float* __restrict__ a2s,
                          const float* __restrict__ W2d, const float* __restrict__ a2d,
                          float* __restrict__ vecs) {
    int t = threadIdx.x;           // 256 threads
    int g = t >> 6, k = t & 63;
    const float* W = (g == 0) ? W1s : (g == 1) ? W1d : (g == 2) ? W2s : W2d;
    const float* a = (g == 0) ? a1s : (g == 1) ? a1d : (g == 2) ? a2s : a2d;
    float s = 0.f;
    #pragma unroll 8
    for (int j = 0; j < 64; ++j) s += W[k * 64 + j] * a[j];
    vecs[t] = s;
}

// ---------------------------------------------------------------------------
// Per-node kernel (32-row tile):
//   hsrc(fp16) = x @ Wsrc ; base = x @ Wl + biases ; asrc = x.vsrc ; adst = x.vdst
// ---------------------------------------------------------------------------
__global__ __launch_bounds__(256) void node_gemm(
    const float* __restrict__ x, const float* __restrict__ Wsrc,
    const float* __restrict__ Wl, const float* __restrict__ vsrc,
    const float* __restrict__ vdst, const float* __restrict__ bconv,
    const float* __restrict__ blin,
    __half2* __restrict__ hsrc, float* __restrict__ base_out,
    float* __restrict__ asrc, float* __restrict__ adst, int n) {
    __shared__ float Ws[64 * 64];
    __shared__ float Wls[64 * 64];
    __shared__ float xs[32 * 65];
    __shared__ float bias_s[64], vs_s[64], vd_s[64];

    int tid = threadIdx.x;
    #pragma unroll
    for (int i = 0; i < 16; ++i) {
        int idx = tid + i * 256;
        Ws[idx]  = Wsrc[idx];
        Wls[idx] = Wl[idx];
    }
    if (tid < 64) {
        bias_s[tid] = bconv[tid] + blin[tid];
        vs_s[tid]   = vsrc[tid];
        vd_s[tid]   = vdst[tid];
    }
    int row0 = blockIdx.x * 32;
    int rows = min(32, n - row0);
    #pragma unroll
    for (int i = 0; i < 8; ++i) {
        int idx = tid + i * 256;
        int r = idx >> 6, cc = idx & 63;
        if (r < rows) xs[r * 65 + cc] = x[(row0 + r) * 64 + cc];
    }
    __syncthreads();

    int r = tid >> 3, cg = tid & 7, c0 = cg * 8;
    if (r >= rows) return;

    float4 h0 = {0, 0, 0, 0}, h1 = {0, 0, 0, 0};
    float4 l0 = {0, 0, 0, 0}, l1 = {0, 0, 0, 0};
    float as = 0.f, ad = 0.f;
    #pragma unroll 8
    for (int k = 0; k < 64; ++k) {
        float xv = xs[r * 65 + k];
        float4 wa = *(const float4*)&Ws[(k << 6) + c0];
        float4 wb = *(const float4*)&Ws[(k << 6) + c0 + 4];
        float4 la = *(const float4*)&Wls[(k << 6) + c0];
        float4 lb = *(const float4*)&Wls[(k << 6) + c0 + 4];
        h0.x += xv * wa.x; h0.y += xv * wa.y; h0.z += xv * wa.z; h0.w += xv * wa.w;
        h1.x += xv * wb.x; h1.y += xv * wb.y; h1.z += xv * wb.z; h1.w += xv * wb.w;
        l0.x += xv * la.x; l0.y += xv * la.y; l0.z += xv * la.z; l0.w += xv * la.w;
        l1.x += xv * lb.x; l1.y += xv * lb.y; l1.z += xv * lb.z; l1.w += xv * lb.w;
        as += xv * vs_s[k];
        ad += xv * vd_s[k];
    }
    int rg = row0 + r;
    // pack 8 channels into 4 half2 and store as one 16B write
    float4 pack;
    ((__half2*)&pack)[0] = __floats2half2_rn(h0.x, h0.y);
    ((__half2*)&pack)[1] = __floats2half2_rn(h0.z, h0.w);
    ((__half2*)&pack)[2] = __floats2half2_rn(h1.x, h1.y);
    ((__half2*)&pack)[3] = __floats2half2_rn(h1.z, h1.w);
    *(float4*)&hsrc[(size_t)rg * 32 + (c0 >> 1)] = pack;

    float4 bA = *(const float4*)&bias_s[c0];
    float4 bB = *(const float4*)&bias_s[c0 + 4];
    l0.x += bA.x; l0.y += bA.y; l0.z += bA.z; l0.w += bA.w;
    l1.x += bB.x; l1.y += bB.y; l1.z += bB.z; l1.w += bB.w;
    *(float4*)&base_out[rg * 64 + c0]     = l0;
    *(float4*)&base_out[rg * 64 + c0 + 4] = l1;
    if (cg == 0) { asrc[rg] = as; adst[rg] = ad; }
}

// ---------------------------------------------------------------------------
// Pass 1: coarse bucket histogram (bucket = dst >> 9). LDS-aggregated.
// ---------------------------------------------------------------------------
__global__ __launch_bounds__(256) void bucket_hist(const int* __restrict__ dst,
                                                   int* __restrict__ bcnt, int E, int K) {
    __shared__ int h[128];
    int t = threadIdx.x;
    if (t < 128) h[t] = 0;
    __syncthreads();
    int base = blockIdx.x * 2048;
    #pragma unroll
    for (int i = 0; i < 8; ++i) {
        int idx = base + i * 256 + t;
        if (idx < E) atomicAdd(&h[dst[idx] >> BSHIFT], 1);
    }
    __syncthreads();
    if (t < K && h[t]) atomicAdd(&bcnt[t], h[t]);
}

// tiny scan over K buckets; also seeds global cursors and rowptr[N]
__global__ void bucket_scan(const int* __restrict__ bcnt, int* __restrict__ bbase,
                            int* __restrict__ gcur, int* __restrict__ rowptr,
                            int K, int N, int E) {
    if (threadIdx.x == 0 && blockIdx.x == 0) {
        int run = 0;
        for (int i = 0; i < K; ++i) { bbase[i] = run; gcur[i] = run; run += bcnt[i]; }
        bbase[K] = run;
        rowptr[N] = E;
    }
}

// ---------------------------------------------------------------------------
// Pass 2: bin edges into bucket regions, packed (src<<9 | dst&511).
// ---------------------------------------------------------------------------
__global__ __launch_bounds__(256) void bin_scatter(const int* __restrict__ src,
                                                   const int* __restrict__ dst,
                                                   int* __restrict__ gcur,
                                                   unsigned* __restrict__ binned,
                                                   int E, int K) {
    __shared__ int h[128], cbase[128], cur[128];
    int t = threadIdx.x;
    if (t < 128) h[t] = 0;
    __syncthreads();
    int base = blockIdx.x * 2048;
    #pragma unroll
    for (int i = 0; i < 8; ++i) {
        int idx = base + i * 256 + t;
        if (idx < E) atomicAdd(&h[dst[idx] >> BSHIFT], 1);
    }
    __syncthreads();
    if (t < K) {
        cbase[t] = h[t] ? atomicAdd(&gcur[t], h[t]) : 0;
        cur[t] = 0;
    }
    __syncthreads();
    #pragma unroll
    for (int i = 0; i < 8; ++i) {
        int idx = base + i * 256 + t;
        if (idx < E) {
            int d = dst[idx], s = src[idx];
            int b = d >> BSHIFT;
            int pos = cbase[b] + atomicAdd(&cur[b], 1);
            binned[pos] = ((unsigned)s << BSHIFT) | (unsigned)(d & (BNODES - 1));
        }
    }
}

// ---------------------------------------------------------------------------
// Pass 3: one block per bucket. LDS-stage, local hist+scan, in-place scatter.
// ---------------------------------------------------------------------------
__global__ __launch_bounds__(1024) void local_csr(const unsigned* __restrict__ binned_in,
                                                  int* __restrict__ ssrc_out,   // same buffer
                                                  const int* __restrict__ bbase,
                                                  int* __restrict__ rowptr, int N) {
    __shared__ int lh[BNODES];     // hist, later cursor
    __shared__ int lex[BNODES];    // exclusive prefix
    __shared__ unsigned ebuf[ECAP];
    int b = blockIdx.x, t = threadIdx.x;
    int base = bbase[b];
    int cnt = min(bbase[b + 1] - base, ECAP);
    if (t < BNODES) lh[t] = 0;
    __syncthreads();
    for (int i = t; i < cnt; i += 1024) {
        unsigned e = binned_in[base + i];
        ebuf[i] = e;
        atomicAdd(&lh[e & (BNODES - 1)], 1);
    }
    __syncthreads();
    if (t < BNODES) lex[t] = lh[t];
    __syncthreads();
    for (int off = 1; off < BNODES; off <<= 1) {
        int add = 0;
        if (t < BNODES && t >= off) add = lex[t - off];
        __syncthreads();
        if (t < BNODES) lex[t] += add;
        __syncthreads();
    }
    int exc = 0;
    if (t < BNODES) exc = lex[t] - lh[t];
    __syncthreads();
    if (t < BNODES) { lex[t] = exc; lh[t] = exc; }   // lh becomes cursor
    __syncthreads();
    int node = b * BNODES + t;
    if (t < BNODES && node < N) rowptr[node] = base + lex[t];
    for (int i = t; i < cnt; i += 1024) {
        unsigned e = ebuf[i];
        int pos = atomicAdd(&lh[e & (BNODES - 1)], 1);
        ssrc_out[base + pos] = (int)(e >> BSHIFT);
    }
}

// ---------------------------------------------------------------------------
// Fused softmax + aggregation + residual + relu. One wave per dst node.
// half2 channels: 32 lanes cover 64 channels, so the wave's two 32-lane
// halves process TWO edges per iteration; combined via shfl_xor(32) at end.
// ---------------------------------------------------------------------------
__global__ __launch_bounds__(256) void gat_aggregate(
    const int* __restrict__ rowptr, const int* __restrict__ ssrc,
    const float* __restrict__ asrc, const float* __restrict__ adst,
    const __half2* __restrict__ hsrc, const float* __restrict__ base,
    float* __restrict__ out, int N) {
    int d = blockIdx.x * 4 + (threadIdx.x >> 6);
    int lane = threadIdx.x & 63;
    int half_id = lane >> 5;       // which edge of the pair
    int c2 = lane & 31;            // half2 index: channels 2*c2, 2*c2+1
    if (d >= N) return;
    int beg = rowptr[d], end = rowptr[d + 1];
    float ad = adst[d];
    float sumw = 0.f, accx = 0.f, accy = 0.f;

    int j = beg + half_id;
    // 2 edges per half per iteration (4 per wave) -> 2 independent load chains
    for (; j + 2 < end; j += 4) {
        int s0 = ssrc[j], s1 = ssrc[j + 2];
        float e0 = asrc[s0] + ad, e1 = asrc[s1] + ad;
        e0 = (e0 >= 0.f) ? e0 : NEG * e0;
        e1 = (e1 >= 0.f) ? e1 : NEG * e1;
        float w0 = __expf(e0), w1 = __expf(e1);
        float2 h0 = __half22float2(hsrc[(size_t)s0 * 32 + c2]);
        float2 h1 = __half22float2(hsrc[(size_t)s1 * 32 + c2]);
        sumw += w0 + w1;
        accx += w0 * h0.x + w1 * h1.x;
        accy += w0 * h0.y + w1 * h1.y;
    }
    if (j < end) {
        int s = ssrc[j];
        float e = asrc[s] + ad;
        e = (e >= 0.f) ? e : NEG * e;
        float w = __expf(e);
        float2 h = __half22float2(hsrc[(size_t)s * 32 + c2]);
        sumw += w;
        accx += w * h.x;
        accy += w * h.y;
    }
    // combine the two 32-lane halves
    accx += __shfl_xor(accx, 32, 64);
    accy += __shfl_xor(accy, 32, 64);
    sumw += __shfl_xor(sumw, 32, 64);

    if (half_id == 0) {
        float2 b2 = *(const float2*)&base[(size_t)d * 64 + 2 * c2];
        float invw = (sumw > 0.f) ? 1.f / sumw : 0.f;
        float2 o;
        o.x = fmaxf(b2.x + accx * invw, 0.f);
        o.y = fmaxf(b2.y + accy * invw, 0.f);
        *(float2*)&out[(size_t)d * 64 + 2 * c2] = o;
    }
}

// ---------------------------------------------------------------------------
extern "C" void kernel_launch(void* const* d_in, const int* in_sizes, int n_in,
                              void* d_out, int out_size, void* d_ws, size_t ws_size,
                              hipStream_t stream) {
    const float* x    = (const float*)d_in[0];
    const int*   ei   = (const int*)d_in[1];
    const float* W1s  = (const float*)d_in[2];
    const float* W1d  = (const float*)d_in[3];
    const float* a1s  = (const float*)d_in[4];
    const float* a1d  = (const float*)d_in[5];
    const float* b1   = (const float*)d_in[6];
    const float* Wl1  = (const float*)d_in[7];
    const float* bl1  = (const float*)d_in[8];
    const float* W2s  = (const float*)d_in[9];
    const float* W2d  = (const float*)d_in[10];
    const float* a2s  = (const float*)d_in[11];
    const float* a2d  = (const float*)d_in[12];
    const float* b2   = (const float*)d_in[13];
    const float* Wl2  = (const float*)d_in[14];
    const float* bl2  = (const float*)d_in[15];

    const int N = in_sizes[0] / 64;          // 50000
    const int E = in_sizes[1] / 2;           // 1200000
    const int* src = ei;
    const int* dst = ei + E;
    const int K = (N + BNODES - 1) >> BSHIFT;  // 98 buckets (<=128)

    float* ws = (float*)d_ws;
    size_t o = 0;
    __half2* hsrcH = (__half2*)(ws + o); o += (size_t)N * 32;   // fp16 [N][64]
    float* base   = ws + o; o += (size_t)N * 64;
    float* asrc   = ws + o; o += N;
    float* adst   = ws + o; o += N;
    float* vecs   = ws + o; o += 256;
    int* rowptr = (int*)(ws + o); o += N + 1;
    int* bcnt   = (int*)(ws + o); o += 128;
    int* bbase  = (int*)(ws + o); o += 129;
    int* gcur   = (int*)(ws + o); o += 128;
    unsigned* binned = (unsigned*)(ws + o); o += E;   // also final ssrc (in-place)
    int* ssrc = (int*)binned;

    float* hmid = (float*)d_out;  // conv1 output scratch; conv2 overwrites d_out last

    prep_vecs<<<1, 256, 0, stream>>>(W1s, a1s, W1d, a1d, W2s, a2s, W2d, a2d, vecs);

    // ---- CSR build via two-level LDS binning (once; shared by both convs) ----
    hipMemsetAsync(bcnt, 0, 128 * sizeof(int), stream);
    const int EB = (E + 2047) / 2048;
    bucket_hist<<<EB, 256, 0, stream>>>(dst, bcnt, E, K);
    bucket_scan<<<1, 64, 0, stream>>>(bcnt, bbase, gcur, rowptr, K, N, E);
    bin_scatter<<<EB, 256, 0, stream>>>(src, dst, gcur, binned, E, K);
    local_csr<<<K, 1024, 0, stream>>>(binned, ssrc, bbase, rowptr, N);

    // ---- conv1 ----
    node_gemm<<<(N + 31) / 32, 256, 0, stream>>>(x, W1s, Wl1, vecs, vecs + 64,
                                                 b1, bl1, hsrcH, base, asrc, adst, N);
    gat_aggregate<<<(N + 3) / 4, 256, 0, stream>>>(rowptr, ssrc, asrc, adst,
                                                   hsrcH, base, hmid, N);

    // ---- conv2 ----
    node_gemm<<<(N + 31) / 32, 256, 0, stream>>>(hmid, W2s, Wl2, vecs + 128, vecs + 192,
                                                 b2, bl2, hsrcH, base, asrc, adst, N);
    gat_aggregate<<<(N + 3) / 4, 256, 0, stream>>>(rowptr, ssrc, asrc, adst,
                                                   hsrcH, base, (float*)d_out, N);
}

// Round 5
// 296.830 us; speedup vs baseline: 2.8851x; 1.1277x over previous
//
#include <hip/hip_runtime.h>
#include <hip/hip_fp16.h>

#define NEG 0.2f
#define BSHIFT 9
#define BNODES 512          // dst nodes per bucket
#define ECAP 14336          // max edges per bucket (mean ~12288, sd ~110 -> 18 sigma)

// ---------------------------------------------------------------------------
// Precompute folded attention vectors: v[k] = sum_j W[k][j] * att[j]
// ---------------------------------------------------------------------------
__global__ void prep_vecs(const float* __restrict__ W1s, const float* __restrict__ a1s,
                          const float* __restrict__ W1d, const float* __restrict__ a1d,
                          const float* __restrict__ W2s, const float* __restrict__ a2s,
                          const float* __restrict__ W2d, const float* __restrict__ a2d,
                          float* __restrict__ vecs) {
    int t = threadIdx.x;           // 256 threads
    int g = t >> 6, k = t & 63;
    const float* W = (g == 0) ? W1s : (g == 1) ? W1d : (g == 2) ? W2s : W2d;
    const float* a = (g == 0) ? a1s : (g == 1) ? a1d : (g == 2) ? a2s : a2d;
    float s = 0.f;
    #pragma unroll 8
    for (int j = 0; j < 64; ++j) s += W[k * 64 + j] * a[j];
    vecs[t] = s;
}

// ---------------------------------------------------------------------------
// Per-node kernel (64-row tile, 2 rows x 8 cols per thread, fp16 weights in
// LDS so one ds_read_b128 = 8 weight cols):
//   hsrc(fp16) = x @ Wsrc ; base = x @ Wl + biases ; asrc = x.vsrc ; adst = x.vdst
// LDS ~34 KB -> 4 blocks/CU.
// ---------------------------------------------------------------------------
__global__ __launch_bounds__(256) void node_gemm(
    const float* __restrict__ x, const float* __restrict__ Wsrc,
    const float* __restrict__ Wl, const float* __restrict__ vsrc,
    const float* __restrict__ vdst, const float* __restrict__ bconv,
    const float* __restrict__ blin,
    __half2* __restrict__ hsrc, float* __restrict__ base_out,
    float* __restrict__ asrc, float* __restrict__ adst, int n) {
    __shared__ __half WsH[64 * 64];
    __shared__ __half WlH[64 * 64];
    __shared__ float xs[64 * 65];
    __shared__ float bias_s[64], vs_s[64], vd_s[64];

    int tid = threadIdx.x;
    // stage weights as fp16 (vector loads, 8B LDS stores)
    #pragma unroll
    for (int i = 0; i < 4; ++i) {
        int idx4 = tid * 4 + i * 1024;          // float4 index base (elements)
        float4 ws = *(const float4*)&Wsrc[idx4];
        float4 wl = *(const float4*)&Wl[idx4];
        __half2 p0 = __floats2half2_rn(ws.x, ws.y);
        __half2 p1 = __floats2half2_rn(ws.z, ws.w);
        *(__half2*)&WsH[idx4]     = p0;
        *(__half2*)&WsH[idx4 + 2] = p1;
        p0 = __floats2half2_rn(wl.x, wl.y);
        p1 = __floats2half2_rn(wl.z, wl.w);
        *(__half2*)&WlH[idx4]     = p0;
        *(__half2*)&WlH[idx4 + 2] = p1;
    }
    if (tid < 64) {
        bias_s[tid] = bconv[tid] + blin[tid];
        vs_s[tid]   = vsrc[tid];
        vd_s[tid]   = vdst[tid];
    }
    int row0 = blockIdx.x * 64;
    int rows = min(64, n - row0);
    #pragma unroll
    for (int i = 0; i < 16; ++i) {
        int idx = tid + i * 256;
        int r = idx >> 6, cc = idx & 63;
        if (r < rows) xs[r * 65 + cc] = x[(size_t)(row0 + r) * 64 + cc];
    }
    __syncthreads();

    int r0 = (tid >> 3) * 2;          // rows r0, r0+1
    int cg = tid & 7, c0 = cg * 8;
    if (r0 >= rows) return;

    float a0[8], a1[8], b0[8], b1[8];
    #pragma unroll
    for (int i = 0; i < 8; ++i) { a0[i] = a1[i] = b0[i] = b1[i] = 0.f; }
    float as0 = 0.f, ad0 = 0.f, as1 = 0.f, ad1 = 0.f;

    #pragma unroll 8
    for (int k = 0; k < 64; ++k) {
        float xv0 = xs[r0 * 65 + k];
        float xv1 = xs[(r0 + 1) * 65 + k];
        float4 wsv = *(const float4*)&WsH[(k << 6) + c0];   // 8 fp16 weights
        float4 wlv = *(const float4*)&WlH[(k << 6) + c0];
        const __half2* hs = (const __half2*)&wsv;
        const __half2* hl = (const __half2*)&wlv;
        #pragma unroll
        for (int p = 0; p < 4; ++p) {
            float2 w = __half22float2(hs[p]);
            a0[2*p]   += xv0 * w.x;  a0[2*p+1] += xv0 * w.y;
            a1[2*p]   += xv1 * w.x;  a1[2*p+1] += xv1 * w.y;
            float2 l = __half22float2(hl[p]);
            b0[2*p]   += xv0 * l.x;  b0[2*p+1] += xv0 * l.y;
            b1[2*p]   += xv1 * l.x;  b1[2*p+1] += xv1 * l.y;
        }
        float vsk = vs_s[k], vdk = vd_s[k];
        as0 += xv0 * vsk;  ad0 += xv0 * vdk;
        as1 += xv1 * vsk;  ad1 += xv1 * vdk;
    }

    int rg0 = row0 + r0, rg1 = rg0 + 1;
    bool row1ok = (r0 + 1) < rows;
    // hsrc fp16 packed stores (16B per row)
    float4 pack;
    ((__half2*)&pack)[0] = __floats2half2_rn(a0[0], a0[1]);
    ((__half2*)&pack)[1] = __floats2half2_rn(a0[2], a0[3]);
    ((__half2*)&pack)[2] = __floats2half2_rn(a0[4], a0[5]);
    ((__half2*)&pack)[3] = __floats2half2_rn(a0[6], a0[7]);
    *(float4*)&hsrc[(size_t)rg0 * 32 + (c0 >> 1)] = pack;
    if (row1ok) {
        ((__half2*)&pack)[0] = __floats2half2_rn(a1[0], a1[1]);
        ((__half2*)&pack)[1] = __floats2half2_rn(a1[2], a1[3]);
        ((__half2*)&pack)[2] = __floats2half2_rn(a1[4], a1[5]);
        ((__half2*)&pack)[3] = __floats2half2_rn(a1[6], a1[7]);
        *(float4*)&hsrc[(size_t)rg1 * 32 + (c0 >> 1)] = pack;
    }
    // base stores (+bias)
    float4 bA = *(const float4*)&bias_s[c0];
    float4 bB = *(const float4*)&bias_s[c0 + 4];
    float4 o;
    o.x = b0[0] + bA.x; o.y = b0[1] + bA.y; o.z = b0[2] + bA.z; o.w = b0[3] + bA.w;
    *(float4*)&base_out[(size_t)rg0 * 64 + c0] = o;
    o.x = b0[4] + bB.x; o.y = b0[5] + bB.y; o.z = b0[6] + bB.z; o.w = b0[7] + bB.w;
    *(float4*)&base_out[(size_t)rg0 * 64 + c0 + 4] = o;
    if (row1ok) {
        o.x = b1[0] + bA.x; o.y = b1[1] + bA.y; o.z = b1[2] + bA.z; o.w = b1[3] + bA.w;
        *(float4*)&base_out[(size_t)rg1 * 64 + c0] = o;
        o.x = b1[4] + bB.x; o.y = b1[5] + bB.y; o.z = b1[6] + bB.z; o.w = b1[7] + bB.w;
        *(float4*)&base_out[(size_t)rg1 * 64 + c0 + 4] = o;
    }
    if (cg == 0) {
        asrc[rg0] = as0; adst[rg0] = ad0;
        if (row1ok) { asrc[rg1] = as1; adst[rg1] = ad1; }
    }
}

// ---------------------------------------------------------------------------
// Pass 1: coarse bucket histogram (bucket = dst >> 9). LDS-aggregated.
// ---------------------------------------------------------------------------
__global__ __launch_bounds__(256) void bucket_hist(const int* __restrict__ dst,
                                                   int* __restrict__ bcnt, int E, int K) {
    __shared__ int h[128];
    int t = threadIdx.x;
    if (t < 128) h[t] = 0;
    __syncthreads();
    int base = blockIdx.x * 2048;
    #pragma unroll
    for (int i = 0; i < 8; ++i) {
        int idx = base + i * 256 + t;
        if (idx < E) atomicAdd(&h[dst[idx] >> BSHIFT], 1);
    }
    __syncthreads();
    if (t < K && h[t]) atomicAdd(&bcnt[t], h[t]);
}

// tiny scan over K buckets; also seeds global cursors and rowptr[N]
__global__ void bucket_scan(const int* __restrict__ bcnt, int* __restrict__ bbase,
                            int* __restrict__ gcur, int* __restrict__ rowptr,
                            int K, int N, int E) {
    if (threadIdx.x == 0 && blockIdx.x == 0) {
        int run = 0;
        for (int i = 0; i < K; ++i) { bbase[i] = run; gcur[i] = run; run += bcnt[i]; }
        bbase[K] = run;
        rowptr[N] = E;
    }
}

// ---------------------------------------------------------------------------
// Pass 2: bin edges into bucket regions, packed (src<<9 | dst&511).
// ---------------------------------------------------------------------------
__global__ __launch_bounds__(256) void bin_scatter(const int* __restrict__ src,
                                                   const int* __restrict__ dst,
                                                   int* __restrict__ gcur,
                                                   unsigned* __restrict__ binned,
                                                   int E, int K) {
    __shared__ int h[128], cbase[128], cur[128];
    int t = threadIdx.x;
    if (t < 128) h[t] = 0;
    __syncthreads();
    int base = blockIdx.x * 2048;
    #pragma unroll
    for (int i = 0; i < 8; ++i) {
        int idx = base + i * 256 + t;
        if (idx < E) atomicAdd(&h[dst[idx] >> BSHIFT], 1);
    }
    __syncthreads();
    if (t < K) {
        cbase[t] = h[t] ? atomicAdd(&gcur[t], h[t]) : 0;
        cur[t] = 0;
    }
    __syncthreads();
    #pragma unroll
    for (int i = 0; i < 8; ++i) {
        int idx = base + i * 256 + t;
        if (idx < E) {
            int d = dst[idx], s = src[idx];
            int b = d >> BSHIFT;
            int pos = cbase[b] + atomicAdd(&cur[b], 1);
            binned[pos] = ((unsigned)s << BSHIFT) | (unsigned)(d & (BNODES - 1));
        }
    }
}

// ---------------------------------------------------------------------------
// Pass 3: one block per bucket. LDS-stage, local hist+scan, in-place scatter.
// ---------------------------------------------------------------------------
__global__ __launch_bounds__(1024) void local_csr(const unsigned* __restrict__ binned_in,
                                                  int* __restrict__ ssrc_out,   // same buffer
                                                  const int* __restrict__ bbase,
                                                  int* __restrict__ rowptr, int N) {
    __shared__ int lh[BNODES];     // hist, later cursor
    __shared__ int lex[BNODES];    // exclusive prefix
    __shared__ unsigned ebuf[ECAP];
    int b = blockIdx.x, t = threadIdx.x;
    int base = bbase[b];
    int cnt = min(bbase[b + 1] - base, ECAP);
    if (t < BNODES) lh[t] = 0;
    __syncthreads();
    for (int i = t; i < cnt; i += 1024) {
        unsigned e = binned_in[base + i];
        ebuf[i] = e;
        atomicAdd(&lh[e & (BNODES - 1)], 1);
    }
    __syncthreads();
    if (t < BNODES) lex[t] = lh[t];
    __syncthreads();
    for (int off = 1; off < BNODES; off <<= 1) {
        int add = 0;
        if (t < BNODES && t >= off) add = lex[t - off];
        __syncthreads();
        if (t < BNODES) lex[t] += add;
        __syncthreads();
    }
    int exc = 0;
    if (t < BNODES) exc = lex[t] - lh[t];
    __syncthreads();
    if (t < BNODES) { lex[t] = exc; lh[t] = exc; }   // lh becomes cursor
    __syncthreads();
    int node = b * BNODES + t;
    if (t < BNODES && node < N) rowptr[node] = base + lex[t];
    for (int i = t; i < cnt; i += 1024) {
        unsigned e = ebuf[i];
        int pos = atomicAdd(&lh[e & (BNODES - 1)], 1);
        ssrc_out[base + pos] = (int)(e >> BSHIFT);
    }
}

// ---------------------------------------------------------------------------
// Fused softmax + aggregation + residual + relu. One wave per dst node.
// half2 channels: 32 lanes cover 64 channels; the wave's two 32-lane halves
// process interleaved edges. 4 independent edge chains per half (8/wave/iter)
// for latency hiding.
// ---------------------------------------------------------------------------
__global__ __launch_bounds__(256) void gat_aggregate(
    const int* __restrict__ rowptr, const int* __restrict__ ssrc,
    const float* __restrict__ asrc, const float* __restrict__ adst,
    const __half2* __restrict__ hsrc, const float* __restrict__ base,
    float* __restrict__ out, int N) {
    int d = blockIdx.x * 4 + (threadIdx.x >> 6);
    int lane = threadIdx.x & 63;
    int half_id = lane >> 5;       // which edge parity this half handles
    int c2 = lane & 31;            // half2 index: channels 2*c2, 2*c2+1
    if (d >= N) return;
    int beg = rowptr[d], end = rowptr[d + 1];
    float ad = adst[d];
    float sumw = 0.f, accx = 0.f, accy = 0.f;

    int j = beg + half_id;
    // 4 edges per half per iteration (8 per wave)
    for (; j + 6 < end; j += 8) {
        int s0 = ssrc[j], s1 = ssrc[j + 2], s2 = ssrc[j + 4], s3 = ssrc[j + 6];
        float e0 = asrc[s0] + ad, e1 = asrc[s1] + ad;
        float e2 = asrc[s2] + ad, e3 = asrc[s3] + ad;
        e0 = (e0 >= 0.f) ? e0 : NEG * e0;
        e1 = (e1 >= 0.f) ? e1 : NEG * e1;
        e2 = (e2 >= 0.f) ? e2 : NEG * e2;
        e3 = (e3 >= 0.f) ? e3 : NEG * e3;
        float w0 = __expf(e0), w1 = __expf(e1), w2 = __expf(e2), w3 = __expf(e3);
        float2 h0 = __half22float2(hsrc[(size_t)s0 * 32 + c2]);
        float2 h1 = __half22float2(hsrc[(size_t)s1 * 32 + c2]);
        float2 h2 = __half22float2(hsrc[(size_t)s2 * 32 + c2]);
        float2 h3 = __half22float2(hsrc[(size_t)s3 * 32 + c2]);
        sumw += (w0 + w1) + (w2 + w3);
        accx += w0 * h0.x + w1 * h1.x + w2 * h2.x + w3 * h3.x;
        accy += w0 * h0.y + w1 * h1.y + w2 * h2.y + w3 * h3.y;
    }
    for (; j < end; j += 2) {
        int s = ssrc[j];
        float e = asrc[s] + ad;
        e = (e >= 0.f) ? e : NEG * e;
        float w = __expf(e);
        float2 h = __half22float2(hsrc[(size_t)s * 32 + c2]);
        sumw += w;
        accx += w * h.x;
        accy += w * h.y;
    }
    // combine the two 32-lane halves
    accx += __shfl_xor(accx, 32, 64);
    accy += __shfl_xor(accy, 32, 64);
    sumw += __shfl_xor(sumw, 32, 64);

    if (half_id == 0) {
        float2 b2 = *(const float2*)&base[(size_t)d * 64 + 2 * c2];
        float invw = (sumw > 0.f) ? 1.f / sumw : 0.f;
        float2 o;
        o.x = fmaxf(b2.x + accx * invw, 0.f);
        o.y = fmaxf(b2.y + accy * invw, 0.f);
        *(float2*)&out[(size_t)d * 64 + 2 * c2] = o;
    }
}

// ---------------------------------------------------------------------------
extern "C" void kernel_launch(void* const* d_in, const int* in_sizes, int n_in,
                              void* d_out, int out_size, void* d_ws, size_t ws_size,
                              hipStream_t stream) {
    const float* x    = (const float*)d_in[0];
    const int*   ei   = (const int*)d_in[1];
    const float* W1s  = (const float*)d_in[2];
    const float* W1d  = (const float*)d_in[3];
    const float* a1s  = (const float*)d_in[4];
    const float* a1d  = (const float*)d_in[5];
    const float* b1   = (const float*)d_in[6];
    const float* Wl1  = (const float*)d_in[7];
    const float* bl1  = (const float*)d_in[8];
    const float* W2s  = (const float*)d_in[9];
    const float* W2d  = (const float*)d_in[10];
    const float* a2s  = (const float*)d_in[11];
    const float* a2d  = (const float*)d_in[12];
    const float* b2   = (const float*)d_in[13];
    const float* Wl2  = (const float*)d_in[14];
    const float* bl2  = (const float*)d_in[15];

    const int N = in_sizes[0] / 64;          // 50000
    const int E = in_sizes[1] / 2;           // 1200000
    const int* src = ei;
    const int* dst = ei + E;
    const int K = (N + BNODES - 1) >> BSHIFT;  // 98 buckets (<=128)

    float* ws = (float*)d_ws;
    size_t o = 0;
    __half2* hsrcH = (__half2*)(ws + o); o += (size_t)N * 32;   // fp16 [N][64]
    float* base   = ws + o; o += (size_t)N * 64;
    float* asrc   = ws + o; o += N;
    float* adst   = ws + o; o += N;
    float* vecs   = ws + o; o += 256;
    int* rowptr = (int*)(ws + o); o += N + 1;
    int* bcnt   = (int*)(ws + o); o += 128;
    int* bbase  = (int*)(ws + o); o += 129;
    int* gcur   = (int*)(ws + o); o += 128;
    unsigned* binned = (unsigned*)(ws + o); o += E;   // also final ssrc (in-place)
    int* ssrc = (int*)binned;

    float* hmid = (float*)d_out;  // conv1 output scratch; conv2 overwrites d_out last

    prep_vecs<<<1, 256, 0, stream>>>(W1s, a1s, W1d, a1d, W2s, a2s, W2d, a2d, vecs);

    // ---- CSR build via two-level LDS binning (once; shared by both convs) ----
    hipMemsetAsync(bcnt, 0, 128 * sizeof(int), stream);
    const int EB = (E + 2047) / 2048;
    bucket_hist<<<EB, 256, 0, stream>>>(dst, bcnt, E, K);
    bucket_scan<<<1, 64, 0, stream>>>(bcnt, bbase, gcur, rowptr, K, N, E);
    bin_scatter<<<EB, 256, 0, stream>>>(src, dst, gcur, binned, E, K);
    local_csr<<<K, 1024, 0, stream>>>(binned, ssrc, bbase, rowptr, N);

    // ---- conv1 ----
    node_gemm<<<(N + 63) / 64, 256, 0, stream>>>(x, W1s, Wl1, vecs, vecs + 64,
                                                 b1, bl1, hsrcH, base, asrc, adst, N);
    gat_aggregate<<<(N + 3) / 4, 256, 0, stream>>>(rowptr, ssrc, asrc, adst,
                                                   hsrcH, base, hmid, N);

    // ---- conv2 ----
    node_gemm<<<(N + 63) / 64, 256, 0, stream>>>(hmid, W2s, Wl2, vecs + 128, vecs + 192,
                                                 b2, bl2, hsrcH, base, asrc, adst, N);
    gat_aggregate<<<(N + 3) / 4, 256, 0, stream>>>(rowptr, ssrc, asrc, adst,
                                                   hsrcH, base, (float*)d_out, N);
}

// Round 6
// 260.617 us; speedup vs baseline: 3.2860x; 1.1390x over previous
//
#include <hip/hip_runtime.h>
#include <hip/hip_fp16.h>

#define NEG 0.2f
#define BSHIFT 9
#define BNODES 512          // dst nodes per bucket
#define ECAP 14336          // fixed region per bucket (mean ~12288, sd ~110 -> +18 sigma)

// ---------------------------------------------------------------------------
// Precompute folded attention vectors: v[k] = sum_j W[k][j] * att[j]
// ---------------------------------------------------------------------------
__global__ void prep_vecs(const float* __restrict__ W1s, const float* __restrict__ a1s,
                          const float* __restrict__ W1d, const float* __restrict__ a1d,
                          const float* __restrict__ W2s, const float* __restrict__ a2s,
                          const float* __restrict__ W2d, const float* __restrict__ a2d,
                          float* __restrict__ vecs) {
    int t = threadIdx.x;           // 256 threads
    int g = t >> 6, k = t & 63;
    const float* W = (g == 0) ? W1s : (g == 1) ? W1d : (g == 2) ? W2s : W2d;
    const float* a = (g == 0) ? a1s : (g == 1) ? a1d : (g == 2) ? a2s : a2d;
    float s = 0.f;
    #pragma unroll 8
    for (int j = 0; j < 64; ++j) s += W[k * 64 + j] * a[j];
    vecs[t] = s;
}

// ---------------------------------------------------------------------------
// Per-node kernel (64-row tile, 2 rows x 8 cols per thread, fp16 weights in
// LDS): hsrc(fp16) = x@Wsrc ; base = x@Wl + biases ; asrc = x.vsrc ; adst = x.vdst
// ---------------------------------------------------------------------------
__global__ __launch_bounds__(256) void node_gemm(
    const float* __restrict__ x, const float* __restrict__ Wsrc,
    const float* __restrict__ Wl, const float* __restrict__ vsrc,
    const float* __restrict__ vdst, const float* __restrict__ bconv,
    const float* __restrict__ blin,
    __half2* __restrict__ hsrc, float* __restrict__ base_out,
    float* __restrict__ asrc, float* __restrict__ adst, int n) {
    __shared__ __half WsH[64 * 64];
    __shared__ __half WlH[64 * 64];
    __shared__ float xs[64 * 65];
    __shared__ float bias_s[64], vs_s[64], vd_s[64];

    int tid = threadIdx.x;
    #pragma unroll
    for (int i = 0; i < 4; ++i) {
        int idx4 = tid * 4 + i * 1024;
        float4 ws = *(const float4*)&Wsrc[idx4];
        float4 wl = *(const float4*)&Wl[idx4];
        __half2 p0 = __floats2half2_rn(ws.x, ws.y);
        __half2 p1 = __floats2half2_rn(ws.z, ws.w);
        *(__half2*)&WsH[idx4]     = p0;
        *(__half2*)&WsH[idx4 + 2] = p1;
        p0 = __floats2half2_rn(wl.x, wl.y);
        p1 = __floats2half2_rn(wl.z, wl.w);
        *(__half2*)&WlH[idx4]     = p0;
        *(__half2*)&WlH[idx4 + 2] = p1;
    }
    if (tid < 64) {
        bias_s[tid] = bconv[tid] + blin[tid];
        vs_s[tid]   = vsrc[tid];
        vd_s[tid]   = vdst[tid];
    }
    int row0 = blockIdx.x * 64;
    int rows = min(64, n - row0);
    #pragma unroll
    for (int i = 0; i < 16; ++i) {
        int idx = tid + i * 256;
        int r = idx >> 6, cc = idx & 63;
        if (r < rows) xs[r * 65 + cc] = x[(size_t)(row0 + r) * 64 + cc];
    }
    __syncthreads();

    int r0 = (tid >> 3) * 2;
    int cg = tid & 7, c0 = cg * 8;
    if (r0 >= rows) return;

    float a0[8], a1[8], b0[8], b1[8];
    #pragma unroll
    for (int i = 0; i < 8; ++i) { a0[i] = a1[i] = b0[i] = b1[i] = 0.f; }
    float as0 = 0.f, ad0 = 0.f, as1 = 0.f, ad1 = 0.f;

    #pragma unroll 8
    for (int k = 0; k < 64; ++k) {
        float xv0 = xs[r0 * 65 + k];
        float xv1 = xs[(r0 + 1) * 65 + k];
        float4 wsv = *(const float4*)&WsH[(k << 6) + c0];
        float4 wlv = *(const float4*)&WlH[(k << 6) + c0];
        const __half2* hs = (const __half2*)&wsv;
        const __half2* hl = (const __half2*)&wlv;
        #pragma unroll
        for (int p = 0; p < 4; ++p) {
            float2 w = __half22float2(hs[p]);
            a0[2*p]   += xv0 * w.x;  a0[2*p+1] += xv0 * w.y;
            a1[2*p]   += xv1 * w.x;  a1[2*p+1] += xv1 * w.y;
            float2 l = __half22float2(hl[p]);
            b0[2*p]   += xv0 * l.x;  b0[2*p+1] += xv0 * l.y;
            b1[2*p]   += xv1 * l.x;  b1[2*p+1] += xv1 * l.y;
        }
        float vsk = vs_s[k], vdk = vd_s[k];
        as0 += xv0 * vsk;  ad0 += xv0 * vdk;
        as1 += xv1 * vsk;  ad1 += xv1 * vdk;
    }

    int rg0 = row0 + r0, rg1 = rg0 + 1;
    bool row1ok = (r0 + 1) < rows;
    float4 pack;
    ((__half2*)&pack)[0] = __floats2half2_rn(a0[0], a0[1]);
    ((__half2*)&pack)[1] = __floats2half2_rn(a0[2], a0[3]);
    ((__half2*)&pack)[2] = __floats2half2_rn(a0[4], a0[5]);
    ((__half2*)&pack)[3] = __floats2half2_rn(a0[6], a0[7]);
    *(float4*)&hsrc[(size_t)rg0 * 32 + (c0 >> 1)] = pack;
    if (row1ok) {
        ((__half2*)&pack)[0] = __floats2half2_rn(a1[0], a1[1]);
        ((__half2*)&pack)[1] = __floats2half2_rn(a1[2], a1[3]);
        ((__half2*)&pack)[2] = __floats2half2_rn(a1[4], a1[5]);
        ((__half2*)&pack)[3] = __floats2half2_rn(a1[6], a1[7]);
        *(float4*)&hsrc[(size_t)rg1 * 32 + (c0 >> 1)] = pack;
    }
    float4 bA = *(const float4*)&bias_s[c0];
    float4 bB = *(const float4*)&bias_s[c0 + 4];
    float4 o;
    o.x = b0[0] + bA.x; o.y = b0[1] + bA.y; o.z = b0[2] + bA.z; o.w = b0[3] + bA.w;
    *(float4*)&base_out[(size_t)rg0 * 64 + c0] = o;
    o.x = b0[4] + bB.x; o.y = b0[5] + bB.y; o.z = b0[6] + bB.z; o.w = b0[7] + bB.w;
    *(float4*)&base_out[(size_t)rg0 * 64 + c0 + 4] = o;
    if (row1ok) {
        o.x = b1[0] + bA.x; o.y = b1[1] + bA.y; o.z = b1[2] + bA.z; o.w = b1[3] + bA.w;
        *(float4*)&base_out[(size_t)rg1 * 64 + c0] = o;
        o.x = b1[4] + bB.x; o.y = b1[5] + bB.y; o.z = b1[6] + bB.z; o.w = b1[7] + bB.w;
        *(float4*)&base_out[(size_t)rg1 * 64 + c0 + 4] = o;
    }
    if (cg == 0) {
        asrc[rg0] = as0; adst[rg0] = ad0;
        if (row1ok) { asrc[rg1] = as1; adst[rg1] = ad1; }
    }
}

// ---------------------------------------------------------------------------
// Bin edges into FIXED bucket regions (b*ECAP), packed (src<<9 | dst&511).
// Per-block LDS hist -> one chunk reservation per (block,bucket) -> contiguous
// writes. gcur must be zeroed before launch.
// ---------------------------------------------------------------------------
__global__ __launch_bounds__(256) void bin_scatter(const int* __restrict__ src,
                                                   const int* __restrict__ dst,
                                                   int* __restrict__ gcur,
                                                   unsigned* __restrict__ binned,
                                                   int E, int K) {
    __shared__ int h[128], cbase[128], cur[128];
    int t = threadIdx.x;
    if (t < 128) h[t] = 0;
    __syncthreads();
    int base = blockIdx.x * 2048;
    #pragma unroll
    for (int i = 0; i < 8; ++i) {
        int idx = base + i * 256 + t;
        if (idx < E) atomicAdd(&h[dst[idx] >> BSHIFT], 1);
    }
    __syncthreads();
    if (t < K) {
        cbase[t] = t * ECAP + (h[t] ? atomicAdd(&gcur[t], h[t]) : 0);
        cur[t] = 0;
    }
    __syncthreads();
    #pragma unroll
    for (int i = 0; i < 8; ++i) {
        int idx = base + i * 256 + t;
        if (idx < E) {
            int d = dst[idx], s = src[idx];
            int b = d >> BSHIFT;
            int pos = cbase[b] + atomicAdd(&cur[b], 1);
            binned[pos] = ((unsigned)s << BSHIFT) | (unsigned)(d & (BNODES - 1));
        }
    }
}

// ---------------------------------------------------------------------------
// One block per bucket: LDS-stage, local hist+scan, emit rowbeg/rowend,
// scatter src back in place over the bucket region.
// ---------------------------------------------------------------------------
__global__ __launch_bounds__(1024) void local_csr(const unsigned* __restrict__ binned_in,
                                                  int* __restrict__ ssrc_out,   // same buffer
                                                  const int* __restrict__ gcur,
                                                  int* __restrict__ rowbeg,
                                                  int* __restrict__ rowend, int N) {
    __shared__ int lh[BNODES];     // hist, later cursor
    __shared__ int lex[BNODES];    // inclusive prefix
    __shared__ unsigned ebuf[ECAP];
    int b = blockIdx.x, t = threadIdx.x;
    int base = b * ECAP;
    int cnt = min(gcur[b], ECAP);
    if (t < BNODES) lh[t] = 0;
    __syncthreads();
    for (int i = t; i < cnt; i += 1024) {
        unsigned e = binned_in[base + i];
        ebuf[i] = e;
        atomicAdd(&lh[e & (BNODES - 1)], 1);
    }
    __syncthreads();
    if (t < BNODES) lex[t] = lh[t];
    __syncthreads();
    for (int off = 1; off < BNODES; off <<= 1) {
        int add = 0;
        if (t < BNODES && t >= off) add = lex[t - off];
        __syncthreads();
        if (t < BNODES) lex[t] += add;
        __syncthreads();
    }
    int node = b * BNODES + t;
    int excv = 0;
    if (t < BNODES) {
        excv = lex[t] - lh[t];
        if (node < N) {
            rowbeg[node] = base + excv;
            rowend[node] = base + lex[t];
        }
    }
    __syncthreads();
    if (t < BNODES) lh[t] = excv;    // lh becomes cursor
    __syncthreads();
    for (int i = t; i < cnt; i += 1024) {
        unsigned e = ebuf[i];
        int pos = atomicAdd(&lh[e & (BNODES - 1)], 1);
        ssrc_out[base + pos] = (int)(e >> BSHIFT);
    }
}

// ---------------------------------------------------------------------------
// Fused softmax + aggregation + residual + relu. One wave per dst node.
// Two-phase: (1) lanes compute src+weight for up to 64 edges in parallel;
// (2) shfl-broadcast (s,w), each 32-lane half gathers one edge's 64 fp16
// channels (half2/lane) and FMAs. Halves combined via shfl_xor(32).
// ---------------------------------------------------------------------------
__global__ __launch_bounds__(256) void gat_aggregate(
    const int* __restrict__ rowbeg, const int* __restrict__ rowend,
    const int* __restrict__ ssrc,
    const float* __restrict__ asrc, const float* __restrict__ adst,
    const __half2* __restrict__ hsrc, const float* __restrict__ base,
    float* __restrict__ out, int N) {
    int d = blockIdx.x * 4 + (threadIdx.x >> 6);
    int lane = threadIdx.x & 63;
    int half_id = lane >> 5;
    int c2 = lane & 31;
    if (d >= N) return;
    int beg = rowbeg[d], end = rowend[d];
    float ad = adst[d];
    float sumw = 0.f, accx = 0.f, accy = 0.f;

    while (beg < end) {
        int nb = min(64, end - beg);
        // phase 1: edge weights, lane-parallel
        int s_l = 0; float w_l = 0.f;
        if (lane < nb) {
            s_l = ssrc[beg + lane];
            float e = asrc[s_l] + ad;
            e = (e >= 0.f) ? e : NEG * e;
            w_l = __expf(e);
        }
        // phase 2: gather+accumulate, 2 edges per iter (unrolled to 4)
        int i = 0;
        for (; i + 3 < nb; i += 4) {
            int ia = i + half_id, ib = i + 2 + half_id;
            int   sa = __shfl(s_l, ia, 64), sb = __shfl(s_l, ib, 64);
            float wa = __shfl(w_l, ia, 64), wb = __shfl(w_l, ib, 64);
            float2 ha = __half22float2(hsrc[(size_t)sa * 32 + c2]);
            float2 hb = __half22float2(hsrc[(size_t)sb * 32 + c2]);
            sumw += wa + wb;
            accx += wa * ha.x + wb * hb.x;
            accy += wa * ha.y + wb * hb.y;
        }
        for (; i < nb; i += 2) {
            int idx = i + half_id;            // idx<=nb; lanes >=nb carry w=0,s=0
            int   s = __shfl(s_l, idx, 64);
            float w = __shfl(w_l, idx, 64);
            float2 h = __half22float2(hsrc[(size_t)s * 32 + c2]);
            sumw += w;
            accx += w * h.x;
            accy += w * h.y;
        }
        beg += nb;
    }
    accx += __shfl_xor(accx, 32, 64);
    accy += __shfl_xor(accy, 32, 64);
    sumw += __shfl_xor(sumw, 32, 64);

    if (half_id == 0) {
        float2 b2 = *(const float2*)&base[(size_t)d * 64 + 2 * c2];
        float invw = (sumw > 0.f) ? 1.f / sumw : 0.f;
        float2 o;
        o.x = fmaxf(b2.x + accx * invw, 0.f);
        o.y = fmaxf(b2.y + accy * invw, 0.f);
        *(float2*)&out[(size_t)d * 64 + 2 * c2] = o;
    }
}

// ---------------------------------------------------------------------------
extern "C" void kernel_launch(void* const* d_in, const int* in_sizes, int n_in,
                              void* d_out, int out_size, void* d_ws, size_t ws_size,
                              hipStream_t stream) {
    const float* x    = (const float*)d_in[0];
    const int*   ei   = (const int*)d_in[1];
    const float* W1s  = (const float*)d_in[2];
    const float* W1d  = (const float*)d_in[3];
    const float* a1s  = (const float*)d_in[4];
    const float* a1d  = (const float*)d_in[5];
    const float* b1   = (const float*)d_in[6];
    const float* Wl1  = (const float*)d_in[7];
    const float* bl1  = (const float*)d_in[8];
    const float* W2s  = (const float*)d_in[9];
    const float* W2d  = (const float*)d_in[10];
    const float* a2s  = (const float*)d_in[11];
    const float* a2d  = (const float*)d_in[12];
    const float* b2   = (const float*)d_in[13];
    const float* Wl2  = (const float*)d_in[14];
    const float* bl2  = (const float*)d_in[15];

    const int N = in_sizes[0] / 64;          // 50000
    const int E = in_sizes[1] / 2;           // 1200000
    const int* src = ei;
    const int* dst = ei + E;
    const int K = (N + BNODES - 1) >> BSHIFT;  // 98 buckets (<=128)

    float* ws = (float*)d_ws;
    size_t o = 0;
    __half2* hsrcH = (__half2*)(ws + o); o += (size_t)N * 32;   // fp16 [N][64]
    float* base   = ws + o; o += (size_t)N * 64;
    float* asrc   = ws + o; o += N;
    float* adst   = ws + o; o += N;
    float* vecs   = ws + o; o += 256;
    int* rowbeg = (int*)(ws + o); o += N;
    int* rowend = (int*)(ws + o); o += N;
    int* gcur   = (int*)(ws + o); o += 128;
    unsigned* binned = (unsigned*)(ws + o); o += (size_t)K * ECAP;  // also final ssrc
    int* ssrc = (int*)binned;

    float* hmid = (float*)d_out;  // conv1 output scratch; conv2 overwrites d_out last

    prep_vecs<<<1, 256, 0, stream>>>(W1s, a1s, W1d, a1d, W2s, a2s, W2d, a2d, vecs);

    // ---- CSR build: fixed-capacity buckets (no global hist/scan pass) ----
    hipMemsetAsync(gcur, 0, 128 * sizeof(int), stream);
    const int EB = (E + 2047) / 2048;
    bin_scatter<<<EB, 256, 0, stream>>>(src, dst, gcur, binned, E, K);
    local_csr<<<K, 1024, 0, stream>>>(binned, ssrc, gcur, rowbeg, rowend, N);

    // ---- conv1 ----
    node_gemm<<<(N + 63) / 64, 256, 0, stream>>>(x, W1s, Wl1, vecs, vecs + 64,
                                                 b1, bl1, hsrcH, base, asrc, adst, N);
    gat_aggregate<<<(N + 3) / 4, 256, 0, stream>>>(rowbeg, rowend, ssrc, asrc, adst,
                                                   hsrcH, base, hmid, N);

    // ---- conv2 ----
    node_gemm<<<(N + 63) / 64, 256, 0, stream>>>(hmid, W2s, Wl2, vecs + 128, vecs + 192,
                                                 b2, bl2, hsrcH, base, asrc, adst, N);
    gat_aggregate<<<(N + 3) / 4, 256, 0, stream>>>(rowbeg, rowend, ssrc, asrc, adst,
                                                   hsrcH, base, (float*)d_out, N);
}

// Round 7
// 239.958 us; speedup vs baseline: 3.5689x; 1.0861x over previous
//
#include <hip/hip_runtime.h>
#include <hip/hip_fp16.h>

#define NEG 0.2f
#define BSHIFT 9
#define BNODES 512          // dst nodes per bucket
#define ECAP 14336          // fixed region per bucket (mean ~12288, sd ~110 -> +18 sigma)

// ---------------------------------------------------------------------------
// K1: blockIdx < EB -> bin edges into fixed bucket regions (b*ECAP), packed
// (src<<9 | dst&511); blockIdx == EB -> prep folded attention vectors.
// ---------------------------------------------------------------------------
__global__ __launch_bounds__(256) void bin_prep(
    const int* __restrict__ src, const int* __restrict__ dst,
    int* __restrict__ gcur, unsigned* __restrict__ binned, int E, int K,
    const float* __restrict__ W1s, const float* __restrict__ a1s,
    const float* __restrict__ W1d, const float* __restrict__ a1d,
    const float* __restrict__ W2s, const float* __restrict__ a2s,
    const float* __restrict__ W2d, const float* __restrict__ a2d,
    float* __restrict__ vecs) {
    int t = threadIdx.x;
    if (blockIdx.x == gridDim.x - 1) {
        // ---- prep_vecs: v[k] = sum_j W[k][j]*att[j] (4 vectors of 64) ----
        int g = t >> 6, k = t & 63;
        const float* W = (g == 0) ? W1s : (g == 1) ? W1d : (g == 2) ? W2s : W2d;
        const float* a = (g == 0) ? a1s : (g == 1) ? a1d : (g == 2) ? a2s : a2d;
        float s = 0.f;
        #pragma unroll 8
        for (int j = 0; j < 64; ++j) s += W[k * 64 + j] * a[j];
        vecs[t] = s;
        return;
    }
    __shared__ int h[128], cbase[128], cur[128];
    if (t < 128) h[t] = 0;
    __syncthreads();
    int base = blockIdx.x * 2048;
    #pragma unroll
    for (int i = 0; i < 8; ++i) {
        int idx = base + i * 256 + t;
        if (idx < E) atomicAdd(&h[dst[idx] >> BSHIFT], 1);
    }
    __syncthreads();
    if (t < K) {
        cbase[t] = t * ECAP + (h[t] ? atomicAdd(&gcur[t], h[t]) : 0);
        cur[t] = 0;
    }
    __syncthreads();
    #pragma unroll
    for (int i = 0; i < 8; ++i) {
        int idx = base + i * 256 + t;
        if (idx < E) {
            int d = dst[idx], s = src[idx];
            int b = d >> BSHIFT;
            int pos = cbase[b] + atomicAdd(&cur[b], 1);
            binned[pos] = ((unsigned)s << BSHIFT) | (unsigned)(d & (BNODES - 1));
        }
    }
}

// ---------------------------------------------------------------------------
// K2: blockIdx < K -> per-bucket CSR finalize (256 threads, no LDS staging:
// binned re-read from L2; ssrc written to a SEPARATE buffer so no in-place
// hazard). blockIdx >= K -> node_gemm 64-row tile (overlaps with csr blocks).
// ---------------------------------------------------------------------------
__global__ __launch_bounds__(256) void csr_gemm(
    const unsigned* __restrict__ binned, int* __restrict__ ssrc,
    const int* __restrict__ gcur, int* __restrict__ rowbeg, int* __restrict__ rowend,
    const float* __restrict__ x, const float* __restrict__ Wsrc,
    const float* __restrict__ Wl, const float* __restrict__ vsrc,
    const float* __restrict__ vdst, const float* __restrict__ bconv,
    const float* __restrict__ blin,
    __half2* __restrict__ hsrc, float* __restrict__ base_out,
    float* __restrict__ asrc, float* __restrict__ adst, int N, int K) {
    __shared__ union {
        struct { __half WsH[4096]; __half WlH[4096]; float xs[64 * 65];
                 float bias[64]; float vs[64]; float vd[64]; } g;
        struct { int lh[BNODES]; int ps[256]; } c;
    } sm;
    int tid = threadIdx.x;
    int blk = blockIdx.x;

    if (blk < K) {
        // ---------------- local CSR for bucket blk ----------------
        int base = blk * ECAP;
        int cnt = min(gcur[blk], ECAP);
        sm.c.lh[tid] = 0; sm.c.lh[tid + 256] = 0;
        __syncthreads();
        for (int i = tid; i < cnt; i += 256)
            atomicAdd(&sm.c.lh[binned[base + i] & (BNODES - 1)], 1);
        __syncthreads();
        int a0 = sm.c.lh[2 * tid], a1 = sm.c.lh[2 * tid + 1];
        sm.c.ps[tid] = a0 + a1;
        __syncthreads();
        for (int off = 1; off < 256; off <<= 1) {
            int v = (tid >= off) ? sm.c.ps[tid - off] : 0;
            __syncthreads();
            sm.c.ps[tid] += v;
            __syncthreads();
        }
        int exc = sm.c.ps[tid] - (a0 + a1);   // exclusive over node pairs
        int node0 = blk * BNODES + 2 * tid, node1 = node0 + 1;
        if (node0 < N) { rowbeg[node0] = base + exc;      rowend[node0] = base + exc + a0; }
        if (node1 < N) { rowbeg[node1] = base + exc + a0; rowend[node1] = base + exc + a0 + a1; }
        __syncthreads();
        sm.c.lh[2 * tid] = exc; sm.c.lh[2 * tid + 1] = exc + a0;   // cursors
        __syncthreads();
        for (int i = tid; i < cnt; i += 256) {
            unsigned e = binned[base + i];
            int pos = atomicAdd(&sm.c.lh[e & (BNODES - 1)], 1);
            ssrc[base + pos] = (int)(e >> BSHIFT);
        }
        return;
    }

    // ---------------- node_gemm tile ----------------
    int gb = blk - K;
    #pragma unroll
    for (int i = 0; i < 4; ++i) {
        int idx4 = tid * 4 + i * 1024;
        float4 ws = *(const float4*)&Wsrc[idx4];
        float4 wl = *(const float4*)&Wl[idx4];
        *(__half2*)&sm.g.WsH[idx4]     = __floats2half2_rn(ws.x, ws.y);
        *(__half2*)&sm.g.WsH[idx4 + 2] = __floats2half2_rn(ws.z, ws.w);
        *(__half2*)&sm.g.WlH[idx4]     = __floats2half2_rn(wl.x, wl.y);
        *(__half2*)&sm.g.WlH[idx4 + 2] = __floats2half2_rn(wl.z, wl.w);
    }
    if (tid < 64) {
        sm.g.bias[tid] = bconv[tid] + blin[tid];
        sm.g.vs[tid]   = vsrc[tid];
        sm.g.vd[tid]   = vdst[tid];
    }
    int row0 = gb * 64;
    int rows = min(64, N - row0);
    #pragma unroll
    for (int i = 0; i < 16; ++i) {
        int idx = tid + i * 256;
        int r = idx >> 6, cc = idx & 63;
        if (r < rows) sm.g.xs[r * 65 + cc] = x[(size_t)(row0 + r) * 64 + cc];
    }
    __syncthreads();

    int r0 = (tid >> 3) * 2;
    int cg = tid & 7, c0 = cg * 8;
    if (r0 >= rows) return;

    float a0[8], a1[8], b0[8], b1[8];
    #pragma unroll
    for (int i = 0; i < 8; ++i) { a0[i] = a1[i] = b0[i] = b1[i] = 0.f; }
    float as0 = 0.f, ad0 = 0.f, as1 = 0.f, ad1 = 0.f;

    #pragma unroll 8
    for (int k = 0; k < 64; ++k) {
        float xv0 = sm.g.xs[r0 * 65 + k];
        float xv1 = sm.g.xs[(r0 + 1) * 65 + k];
        float4 wsv = *(const float4*)&sm.g.WsH[(k << 6) + c0];
        float4 wlv = *(const float4*)&sm.g.WlH[(k << 6) + c0];
        const __half2* hs = (const __half2*)&wsv;
        const __half2* hl = (const __half2*)&wlv;
        #pragma unroll
        for (int p = 0; p < 4; ++p) {
            float2 w = __half22float2(hs[p]);
            a0[2*p]   += xv0 * w.x;  a0[2*p+1] += xv0 * w.y;
            a1[2*p]   += xv1 * w.x;  a1[2*p+1] += xv1 * w.y;
            float2 l = __half22float2(hl[p]);
            b0[2*p]   += xv0 * l.x;  b0[2*p+1] += xv0 * l.y;
            b1[2*p]   += xv1 * l.x;  b1[2*p+1] += xv1 * l.y;
        }
        float vsk = sm.g.vs[k], vdk = sm.g.vd[k];
        as0 += xv0 * vsk;  ad0 += xv0 * vdk;
        as1 += xv1 * vsk;  ad1 += xv1 * vdk;
    }

    int rg0 = row0 + r0, rg1 = rg0 + 1;
    bool row1ok = (r0 + 1) < rows;
    float4 pack;
    ((__half2*)&pack)[0] = __floats2half2_rn(a0[0], a0[1]);
    ((__half2*)&pack)[1] = __floats2half2_rn(a0[2], a0[3]);
    ((__half2*)&pack)[2] = __floats2half2_rn(a0[4], a0[5]);
    ((__half2*)&pack)[3] = __floats2half2_rn(a0[6], a0[7]);
    *(float4*)&hsrc[(size_t)rg0 * 32 + (c0 >> 1)] = pack;
    if (row1ok) {
        ((__half2*)&pack)[0] = __floats2half2_rn(a1[0], a1[1]);
        ((__half2*)&pack)[1] = __floats2half2_rn(a1[2], a1[3]);
        ((__half2*)&pack)[2] = __floats2half2_rn(a1[4], a1[5]);
        ((__half2*)&pack)[3] = __floats2half2_rn(a1[6], a1[7]);
        *(float4*)&hsrc[(size_t)rg1 * 32 + (c0 >> 1)] = pack;
    }
    float4 bA = *(const float4*)&sm.g.bias[c0];
    float4 bB = *(const float4*)&sm.g.bias[c0 + 4];
    float4 o;
    o.x = b0[0] + bA.x; o.y = b0[1] + bA.y; o.z = b0[2] + bA.z; o.w = b0[3] + bA.w;
    *(float4*)&base_out[(size_t)rg0 * 64 + c0] = o;
    o.x = b0[4] + bB.x; o.y = b0[5] + bB.y; o.z = b0[6] + bB.z; o.w = b0[7] + bB.w;
    *(float4*)&base_out[(size_t)rg0 * 64 + c0 + 4] = o;
    if (row1ok) {
        o.x = b1[0] + bA.x; o.y = b1[1] + bA.y; o.z = b1[2] + bA.z; o.w = b1[3] + bA.w;
        *(float4*)&base_out[(size_t)rg1 * 64 + c0] = o;
        o.x = b1[4] + bB.x; o.y = b1[5] + bB.y; o.z = b1[6] + bB.z; o.w = b1[7] + bB.w;
        *(float4*)&base_out[(size_t)rg1 * 64 + c0 + 4] = o;
    }
    if (cg == 0) {
        asrc[rg0] = as0; adst[rg0] = ad0;
        if (row1ok) { asrc[rg1] = as1; adst[rg1] = ad1; }
    }
}

// ---------------------------------------------------------------------------
// Plain node_gemm (conv2 - no csr blocks to merge with)
// ---------------------------------------------------------------------------
__global__ __launch_bounds__(256) void node_gemm(
    const float* __restrict__ x, const float* __restrict__ Wsrc,
    const float* __restrict__ Wl, const float* __restrict__ vsrc,
    const float* __restrict__ vdst, const float* __restrict__ bconv,
    const float* __restrict__ blin,
    __half2* __restrict__ hsrc, float* __restrict__ base_out,
    float* __restrict__ asrc, float* __restrict__ adst, int n) {
    __shared__ __half WsH[4096];
    __shared__ __half WlH[4096];
    __shared__ float xs[64 * 65];
    __shared__ float bias_s[64], vs_s[64], vd_s[64];

    int tid = threadIdx.x;
    #pragma unroll
    for (int i = 0; i < 4; ++i) {
        int idx4 = tid * 4 + i * 1024;
        float4 ws = *(const float4*)&Wsrc[idx4];
        float4 wl = *(const float4*)&Wl[idx4];
        *(__half2*)&WsH[idx4]     = __floats2half2_rn(ws.x, ws.y);
        *(__half2*)&WsH[idx4 + 2] = __floats2half2_rn(ws.z, ws.w);
        *(__half2*)&WlH[idx4]     = __floats2half2_rn(wl.x, wl.y);
        *(__half2*)&WlH[idx4 + 2] = __floats2half2_rn(wl.z, wl.w);
    }
    if (tid < 64) {
        bias_s[tid] = bconv[tid] + blin[tid];
        vs_s[tid]   = vsrc[tid];
        vd_s[tid]   = vdst[tid];
    }
    int row0 = blockIdx.x * 64;
    int rows = min(64, n - row0);
    #pragma unroll
    for (int i = 0; i < 16; ++i) {
        int idx = tid + i * 256;
        int r = idx >> 6, cc = idx & 63;
        if (r < rows) xs[r * 65 + cc] = x[(size_t)(row0 + r) * 64 + cc];
    }
    __syncthreads();

    int r0 = (tid >> 3) * 2;
    int cg = tid & 7, c0 = cg * 8;
    if (r0 >= rows) return;

    float a0[8], a1[8], b0[8], b1[8];
    #pragma unroll
    for (int i = 0; i < 8; ++i) { a0[i] = a1[i] = b0[i] = b1[i] = 0.f; }
    float as0 = 0.f, ad0 = 0.f, as1 = 0.f, ad1 = 0.f;

    #pragma unroll 8
    for (int k = 0; k < 64; ++k) {
        float xv0 = xs[r0 * 65 + k];
        float xv1 = xs[(r0 + 1) * 65 + k];
        float4 wsv = *(const float4*)&WsH[(k << 6) + c0];
        float4 wlv = *(const float4*)&WlH[(k << 6) + c0];
        const __half2* hs = (const __half2*)&wsv;
        const __half2* hl = (const __half2*)&wlv;
        #pragma unroll
        for (int p = 0; p < 4; ++p) {
            float2 w = __half22float2(hs[p]);
            a0[2*p]   += xv0 * w.x;  a0[2*p+1] += xv0 * w.y;
            a1[2*p]   += xv1 * w.x;  a1[2*p+1] += xv1 * w.y;
            float2 l = __half22float2(hl[p]);
            b0[2*p]   += xv0 * l.x;  b0[2*p+1] += xv0 * l.y;
            b1[2*p]   += xv1 * l.x;  b1[2*p+1] += xv1 * l.y;
        }
        float vsk = vs_s[k], vdk = vd_s[k];
        as0 += xv0 * vsk;  ad0 += xv0 * vdk;
        as1 += xv1 * vsk;  ad1 += xv1 * vdk;
    }

    int rg0 = row0 + r0, rg1 = rg0 + 1;
    bool row1ok = (r0 + 1) < rows;
    float4 pack;
    ((__half2*)&pack)[0] = __floats2half2_rn(a0[0], a0[1]);
    ((__half2*)&pack)[1] = __floats2half2_rn(a0[2], a0[3]);
    ((__half2*)&pack)[2] = __floats2half2_rn(a0[4], a0[5]);
    ((__half2*)&pack)[3] = __floats2half2_rn(a0[6], a0[7]);
    *(float4*)&hsrc[(size_t)rg0 * 32 + (c0 >> 1)] = pack;
    if (row1ok) {
        ((__half2*)&pack)[0] = __floats2half2_rn(a1[0], a1[1]);
        ((__half2*)&pack)[1] = __floats2half2_rn(a1[2], a1[3]);
        ((__half2*)&pack)[2] = __floats2half2_rn(a1[4], a1[5]);
        ((__half2*)&pack)[3] = __floats2half2_rn(a1[6], a1[7]);
        *(float4*)&hsrc[(size_t)rg1 * 32 + (c0 >> 1)] = pack;
    }
    float4 bA = *(const float4*)&bias_s[c0];
    float4 bB = *(const float4*)&bias_s[c0 + 4];
    float4 o;
    o.x = b0[0] + bA.x; o.y = b0[1] + bA.y; o.z = b0[2] + bA.z; o.w = b0[3] + bA.w;
    *(float4*)&base_out[(size_t)rg0 * 64 + c0] = o;
    o.x = b0[4] + bB.x; o.y = b0[5] + bB.y; o.z = b0[6] + bB.z; o.w = b0[7] + bB.w;
    *(float4*)&base_out[(size_t)rg0 * 64 + c0 + 4] = o;
    if (row1ok) {
        o.x = b1[0] + bA.x; o.y = b1[1] + bA.y; o.z = b1[2] + bA.z; o.w = b1[3] + bA.w;
        *(float4*)&base_out[(size_t)rg1 * 64 + c0] = o;
        o.x = b1[4] + bB.x; o.y = b1[5] + bB.y; o.z = b1[6] + bB.z; o.w = b1[7] + bB.w;
        *(float4*)&base_out[(size_t)rg1 * 64 + c0 + 4] = o;
    }
    if (cg == 0) {
        asrc[rg0] = as0; adst[rg0] = ad0;
        if (row1ok) { asrc[rg1] = as1; adst[rg1] = ad1; }
    }
}

// ---------------------------------------------------------------------------
// Fused softmax + aggregation + residual + relu. One wave per dst node.
// Phase 1: 64 lanes compute (src, w) for up to 64 edges in parallel.
// Phase 2: shfl-broadcast; each 32-lane half gathers one edge's 128B fp16 row
// (half2/lane); 4 chains per half (8 edges per wave-iter) for latency hiding.
// ---------------------------------------------------------------------------
__global__ __launch_bounds__(256) void gat_aggregate(
    const int* __restrict__ rowbeg, const int* __restrict__ rowend,
    const int* __restrict__ ssrc,
    const float* __restrict__ asrc, const float* __restrict__ adst,
    const __half2* __restrict__ hsrc, const float* __restrict__ base,
    float* __restrict__ out, int N) {
    int d = blockIdx.x * 4 + (threadIdx.x >> 6);
    int lane = threadIdx.x & 63;
    int half_id = lane >> 5;
    int c2 = lane & 31;
    if (d >= N) return;
    int beg = rowbeg[d], end = rowend[d];
    float ad = adst[d];
    float sumw = 0.f, accx = 0.f, accy = 0.f;

    while (beg < end) {
        int nb = min(64, end - beg);
        int s_l = 0; float w_l = 0.f;
        if (lane < nb) {
            s_l = ssrc[beg + lane];
            float e = asrc[s_l] + ad;
            e = (e >= 0.f) ? e : NEG * e;
            w_l = __expf(e);
        }
        int i = 0;
        for (; i + 7 < nb; i += 8) {
            int i0 = i + half_id, i1 = i + 2 + half_id;
            int i2 = i + 4 + half_id, i3 = i + 6 + half_id;
            int   s0 = __shfl(s_l, i0, 64), s1 = __shfl(s_l, i1, 64);
            int   s2 = __shfl(s_l, i2, 64), s3 = __shfl(s_l, i3, 64);
            float w0 = __shfl(w_l, i0, 64), w1 = __shfl(w_l, i1, 64);
            float w2 = __shfl(w_l, i2, 64), w3 = __shfl(w_l, i3, 64);
            float2 h0 = __half22float2(hsrc[(size_t)s0 * 32 + c2]);
            float2 h1 = __half22float2(hsrc[(size_t)s1 * 32 + c2]);
            float2 h2 = __half22float2(hsrc[(size_t)s2 * 32 + c2]);
            float2 h3 = __half22float2(hsrc[(size_t)s3 * 32 + c2]);
            sumw += (w0 + w1) + (w2 + w3);
            accx += w0 * h0.x + w1 * h1.x + w2 * h2.x + w3 * h3.x;
            accy += w0 * h0.y + w1 * h1.y + w2 * h2.y + w3 * h3.y;
        }
        for (; i + 3 < nb; i += 4) {
            int i0 = i + half_id, i1 = i + 2 + half_id;
            int   s0 = __shfl(s_l, i0, 64), s1 = __shfl(s_l, i1, 64);
            float w0 = __shfl(w_l, i0, 64), w1 = __shfl(w_l, i1, 64);
            float2 h0 = __half22float2(hsrc[(size_t)s0 * 32 + c2]);
            float2 h1 = __half22float2(hsrc[(size_t)s1 * 32 + c2]);
            sumw += w0 + w1;
            accx += w0 * h0.x + w1 * h1.x;
            accy += w0 * h0.y + w1 * h1.y;
        }
        for (; i < nb; i += 2) {
            int idx = i + half_id;            // lanes >= nb carry w=0
            int   s = __shfl(s_l, idx, 64);
            float w = __shfl(w_l, idx, 64);
            float2 h = __half22float2(hsrc[(size_t)s * 32 + c2]);
            sumw += w;
            accx += w * h.x;
            accy += w * h.y;
        }
        beg += nb;
    }
    accx += __shfl_xor(accx, 32, 64);
    accy += __shfl_xor(accy, 32, 64);
    sumw += __shfl_xor(sumw, 32, 64);

    if (half_id == 0) {
        float2 b2 = *(const float2*)&base[(size_t)d * 64 + 2 * c2];
        float invw = (sumw > 0.f) ? 1.f / sumw : 0.f;
        float2 o;
        o.x = fmaxf(b2.x + accx * invw, 0.f);
        o.y = fmaxf(b2.y + accy * invw, 0.f);
        *(float2*)&out[(size_t)d * 64 + 2 * c2] = o;
    }
}

// ---------------------------------------------------------------------------
extern "C" void kernel_launch(void* const* d_in, const int* in_sizes, int n_in,
                              void* d_out, int out_size, void* d_ws, size_t ws_size,
                              hipStream_t stream) {
    const float* x    = (const float*)d_in[0];
    const int*   ei   = (const int*)d_in[1];
    const float* W1s  = (const float*)d_in[2];
    const float* W1d  = (const float*)d_in[3];
    const float* a1s  = (const float*)d_in[4];
    const float* a1d  = (const float*)d_in[5];
    const float* b1   = (const float*)d_in[6];
    const float* Wl1  = (const float*)d_in[7];
    const float* bl1  = (const float*)d_in[8];
    const float* W2s  = (const float*)d_in[9];
    const float* W2d  = (const float*)d_in[10];
    const float* a2s  = (const float*)d_in[11];
    const float* a2d  = (const float*)d_in[12];
    const float* b2   = (const float*)d_in[13];
    const float* Wl2  = (const float*)d_in[14];
    const float* bl2  = (const float*)d_in[15];

    const int N = in_sizes[0] / 64;          // 50000
    const int E = in_sizes[1] / 2;           // 1200000
    const int* src = ei;
    const int* dst = ei + E;
    const int K = (N + BNODES - 1) >> BSHIFT;  // 98 buckets (<=128)

    float* ws = (float*)d_ws;
    size_t o = 0;
    __half2* hsrcH = (__half2*)(ws + o); o += (size_t)N * 32;   // fp16 [N][64]
    float* base   = ws + o; o += (size_t)N * 64;
    float* asrc   = ws + o; o += N;
    float* adst   = ws + o; o += N;
    float* vecs   = ws + o; o += 256;
    int* rowbeg = (int*)(ws + o); o += N;
    int* rowend = (int*)(ws + o); o += N;
    int* gcur   = (int*)(ws + o); o += 128;
    unsigned* binned = (unsigned*)(ws + o); o += (size_t)K * ECAP;
    int* ssrc   = (int*)(ws + o); o += (size_t)K * ECAP;   // separate (no in-place hazard)

    float* hmid = (float*)d_out;  // conv1 output scratch; conv2 overwrites d_out last

    const int EB = (E + 2047) / 2048;

    // ---- K1: bin_scatter (EB blocks) + prep_vecs (1 block) ----
    hipMemsetAsync(gcur, 0, 128 * sizeof(int), stream);
    bin_prep<<<EB + 1, 256, 0, stream>>>(src, dst, gcur, binned, E, K,
                                         W1s, a1s, W1d, a1d, W2s, a2s, W2d, a2d, vecs);

    // ---- K2: local_csr (K blocks) + conv1 node_gemm (782 blocks) ----
    csr_gemm<<<K + (N + 63) / 64, 256, 0, stream>>>(
        binned, ssrc, gcur, rowbeg, rowend,
        x, W1s, Wl1, vecs, vecs + 64, b1, bl1,
        hsrcH, base, asrc, adst, N, K);

    // ---- conv1 aggregate ----
    gat_aggregate<<<(N + 3) / 4, 256, 0, stream>>>(rowbeg, rowend, ssrc, asrc, adst,
                                                   hsrcH, base, hmid, N);

    // ---- conv2 ----
    node_gemm<<<(N + 63) / 64, 256, 0, stream>>>(hmid, W2s, Wl2, vecs + 128, vecs + 192,
                                                 b2, bl2, hsrcH, base, asrc, adst, N);
    gat_aggregate<<<(N + 3) / 4, 256, 0, stream>>>(rowbeg, rowend, ssrc, asrc, adst,
                                                   hsrcH, base, (float*)d_out, N);
}